// Round 1
// baseline (3138.332 us; speedup 1.0000x reference)
//
#include <hip/hip_runtime.h>
#include <cmath>

// Problem constants
#define NB   128      // batch
#define NT   64       // time
#define NV   16000    // vocab
#define NE   128      // emb dim
#define NC   256      // context dim
#define NH   512      // hidden
#define G4   2048     // 4*NH
#define ECK  384      // NE+NC
#define BT   8192     // NB*NT

// ---------------------------------------------------------------------------
// K0: build inp[t*128+b][384] = concat(emb_table[x[b][t]], context[b])
// ---------------------------------------------------------------------------
__global__ void build_inp(const int* __restrict__ x, const float* __restrict__ ctx,
                          const float* __restrict__ emb, float* __restrict__ inp) {
    int f = blockIdx.x * blockDim.x + threadIdx.x;   // float4 index
    const int total = BT * (ECK / 4);
    if (f >= total) return;
    int row = f / (ECK / 4);
    int c4  = f % (ECK / 4);
    int b = row & (NB - 1);
    int c = c4 * 4;
    float4 v;
    if (c < NE) {
        int t = row >> 7;
        int tok = x[b * NT + t];
        v = *(const float4*)(emb + tok * NE + c);
    } else {
        v = *(const float4*)(ctx + b * NC + (c - NE));
    }
    ((float4*)inp)[f] = v;
}

// ---------------------------------------------------------------------------
// K1: xg[row=(t*128+b)][j] = inp[row]·W_ih[j] + b_ih[j] + b_hh[j]
// 128x128 tile, 256 thr, 8x8/thread, K=384 in chunks of 32
// ---------------------------------------------------------------------------
#define KC 32
#define LDL 132

__global__ __launch_bounds__(256, 2) void gemm_xg(
    const float* __restrict__ A,    // inp [BT][384]
    const float* __restrict__ Bw,   // W_ih [2048][384]
    const float* __restrict__ b_ih, const float* __restrict__ b_hh,
    float* __restrict__ xg)         // [BT][2048]
{
    __shared__ float As[KC][LDL];
    __shared__ float Bs[KC][LDL];
    const int tid = threadIdx.x;
    const int tx = tid & 15, ty = tid >> 4;
    const int rowBase = blockIdx.y * 128;
    const int colBase = blockIdx.x * 128;
    float acc[8][8];
#pragma unroll
    for (int i = 0; i < 8; i++)
#pragma unroll
        for (int j = 0; j < 8; j++) acc[i][j] = 0.f;

    for (int kb = 0; kb < ECK; kb += KC) {
#pragma unroll
        for (int l = 0; l < 4; ++l) {
            int f4 = tid + l * 256;
            int r = f4 >> 3, kq = f4 & 7;
            float4 v = *(const float4*)(A + (rowBase + r) * ECK + kb + kq * 4);
            As[kq * 4 + 0][r] = v.x; As[kq * 4 + 1][r] = v.y;
            As[kq * 4 + 2][r] = v.z; As[kq * 4 + 3][r] = v.w;
        }
#pragma unroll
        for (int l = 0; l < 4; ++l) {
            int f4 = tid + l * 256;
            int r = f4 >> 3, kq = f4 & 7;
            float4 v = *(const float4*)(Bw + (colBase + r) * ECK + kb + kq * 4);
            Bs[kq * 4 + 0][r] = v.x; Bs[kq * 4 + 1][r] = v.y;
            Bs[kq * 4 + 2][r] = v.z; Bs[kq * 4 + 3][r] = v.w;
        }
        __syncthreads();
#pragma unroll
        for (int k = 0; k < KC; ++k) {
            float a[8], b[8];
            *(float4*)&a[0] = *(const float4*)&As[k][ty * 4];
            *(float4*)&a[4] = *(const float4*)&As[k][64 + ty * 4];
            *(float4*)&b[0] = *(const float4*)&Bs[k][tx * 4];
            *(float4*)&b[4] = *(const float4*)&Bs[k][64 + tx * 4];
#pragma unroll
            for (int i = 0; i < 8; i++)
#pragma unroll
                for (int j = 0; j < 8; j++)
                    acc[i][j] = fmaf(a[i], b[j], acc[i][j]);
        }
        __syncthreads();
    }
    // epilogue: bias add, float4 stores (cols tx*4..+3 and 64+tx*4..+3)
    float bias[8];
#pragma unroll
    for (int j = 0; j < 8; j++) {
        int col = colBase + ((j < 4) ? tx * 4 + j : 64 + tx * 4 + (j - 4));
        bias[j] = b_ih[col] + b_hh[col];
    }
#pragma unroll
    for (int i = 0; i < 8; i++) {
        int row = rowBase + ((i < 4) ? ty * 4 + i : 64 + ty * 4 + (i - 4));
        float4 lo = { acc[i][0] + bias[0], acc[i][1] + bias[1],
                      acc[i][2] + bias[2], acc[i][3] + bias[3] };
        float4 hi = { acc[i][4] + bias[4], acc[i][5] + bias[5],
                      acc[i][6] + bias[6], acc[i][7] + bias[7] };
        *(float4*)(xg + row * G4 + colBase + tx * 4)      = lo;
        *(float4*)(xg + row * G4 + colBase + 64 + tx * 4) = hi;
    }
}

// ---------------------------------------------------------------------------
// K2: one LSTM step. grid (32 h-blocks, 4 b-blocks), 256 thr.
// Thread (tx,ty): h = hBase+tx, b = bBase+ty*2+{0,1}; 4 gate-dots each.
// B-tile cols c: h_local = c>>2, gate = c&3  -> W_hh row = gate*512 + h.
// ---------------------------------------------------------------------------
#define SKC 128
__global__ __launch_bounds__(256, 2) void lstm_step(
    const float* __restrict__ h_prev, const float* __restrict__ c_prev,
    const float* __restrict__ xg, const float* __restrict__ W_hh,
    float* __restrict__ h_next, float* __restrict__ c_next,
    float* __restrict__ hs, int t)
{
    __shared__ float As[SKC][34];   // h_prev chunk, transposed [k][b]
    __shared__ float Bs[SKC][68];   // W rows chunk, transposed [k][c]
    const int tid = threadIdx.x;
    const int tx = tid & 15, ty = tid >> 4;
    const int hBase = blockIdx.x * 16;
    const int bBase = blockIdx.y * 32;
    float acc[2][4];
#pragma unroll
    for (int e = 0; e < 2; e++)
#pragma unroll
        for (int g = 0; g < 4; g++) acc[e][g] = 0.f;

    for (int kb = 0; kb < NH; kb += SKC) {
        // A: 32 b x 128 k  (1024 f4)
#pragma unroll
        for (int l = 0; l < 4; ++l) {
            int f4 = tid + l * 256;
            int r = f4 >> 5, kq = f4 & 31;
            float4 v = *(const float4*)(h_prev + (bBase + r) * NH + kb + kq * 4);
            As[kq * 4 + 0][r] = v.x; As[kq * 4 + 1][r] = v.y;
            As[kq * 4 + 2][r] = v.z; As[kq * 4 + 3][r] = v.w;
        }
        // B: 64 W-rows x 128 k (2048 f4)
#pragma unroll
        for (int l = 0; l < 8; ++l) {
            int f4 = tid + l * 256;
            int c = f4 >> 5, kq = f4 & 31;
            int wrow = (c & 3) * NH + hBase + (c >> 2);
            float4 v = *(const float4*)(W_hh + wrow * NH + kb + kq * 4);
            Bs[kq * 4 + 0][c] = v.x; Bs[kq * 4 + 1][c] = v.y;
            Bs[kq * 4 + 2][c] = v.z; Bs[kq * 4 + 3][c] = v.w;
        }
        __syncthreads();
#pragma unroll
        for (int k = 0; k < SKC; ++k) {
            float2 a = *(const float2*)&As[k][ty * 2];
            float4 b = *(const float4*)&Bs[k][tx * 4];
            acc[0][0] = fmaf(a.x, b.x, acc[0][0]);
            acc[0][1] = fmaf(a.x, b.y, acc[0][1]);
            acc[0][2] = fmaf(a.x, b.z, acc[0][2]);
            acc[0][3] = fmaf(a.x, b.w, acc[0][3]);
            acc[1][0] = fmaf(a.y, b.x, acc[1][0]);
            acc[1][1] = fmaf(a.y, b.y, acc[1][1]);
            acc[1][2] = fmaf(a.y, b.z, acc[1][2]);
            acc[1][3] = fmaf(a.y, b.w, acc[1][3]);
        }
        __syncthreads();
    }
    // epilogue: gates + state update
    const int h = hBase + tx;
#pragma unroll
    for (int e = 0; e < 2; e++) {
        int b = bBase + ty * 2 + e;
        const float* xgr = xg + (t * NB + b) * G4;
        float gi = acc[e][0] + xgr[h];
        float gf = acc[e][1] + xgr[NH + h];
        float gg = acc[e][2] + xgr[2 * NH + h];
        float go = acc[e][3] + xgr[3 * NH + h];
        float i_ = 1.f / (1.f + __expf(-gi));
        float f_ = 1.f / (1.f + __expf(-gf));
        float o_ = 1.f / (1.f + __expf(-go));
        float cp = c_prev[b * NH + h];
        float cn = f_ * cp + i_ * tanhf(gg);
        float hn = o_ * tanhf(cn);
        c_next[b * NH + h] = cn;
        h_next[b * NH + h] = hn;
        hs[(b * NT + t) * NH + h] = hn;   // decoder rows ordered b*T+t
    }
}

// ---------------------------------------------------------------------------
// K3: decoder GEMM + fused log-softmax pieces.
// logits are tiny (|logit|<~2): no max subtraction needed for LSE.
// Per (rowblock, vblock): partial sum(exp) -> atomicAdd; picked logit where v==y.
// ---------------------------------------------------------------------------
__global__ __launch_bounds__(256, 2) void decoder_lse(
    const float* __restrict__ A,     // hs [BT][512], rows b*T+t
    const float* __restrict__ Bw,    // W_dec [16000][512]
    const float* __restrict__ b_dec,
    const int* __restrict__ y,       // [B][T] flat == row index
    float* __restrict__ sumexp,      // [BT]
    float* __restrict__ picked)      // [BT]
{
    __shared__ float As[KC][LDL];
    __shared__ float Bs[KC][LDL];
    const int tid = threadIdx.x;
    const int tx = tid & 15, ty = tid >> 4;
    const int rowBase = blockIdx.y * 128;
    const int colBase = blockIdx.x * 128;
    float acc[8][8];
#pragma unroll
    for (int i = 0; i < 8; i++)
#pragma unroll
        for (int j = 0; j < 8; j++) acc[i][j] = 0.f;

    for (int kb = 0; kb < NH; kb += KC) {
#pragma unroll
        for (int l = 0; l < 4; ++l) {
            int f4 = tid + l * 256;
            int r = f4 >> 3, kq = f4 & 7;
            float4 v = *(const float4*)(A + (rowBase + r) * NH + kb + kq * 4);
            As[kq * 4 + 0][r] = v.x; As[kq * 4 + 1][r] = v.y;
            As[kq * 4 + 2][r] = v.z; As[kq * 4 + 3][r] = v.w;
        }
#pragma unroll
        for (int l = 0; l < 4; ++l) {
            int f4 = tid + l * 256;
            int r = f4 >> 3, kq = f4 & 7;
            float4 v = *(const float4*)(Bw + (colBase + r) * NH + kb + kq * 4);
            Bs[kq * 4 + 0][r] = v.x; Bs[kq * 4 + 1][r] = v.y;
            Bs[kq * 4 + 2][r] = v.z; Bs[kq * 4 + 3][r] = v.w;
        }
        __syncthreads();
#pragma unroll
        for (int k = 0; k < KC; ++k) {
            float a[8], b[8];
            *(float4*)&a[0] = *(const float4*)&As[k][ty * 4];
            *(float4*)&a[4] = *(const float4*)&As[k][64 + ty * 4];
            *(float4*)&b[0] = *(const float4*)&Bs[k][tx * 4];
            *(float4*)&b[4] = *(const float4*)&Bs[k][64 + tx * 4];
#pragma unroll
            for (int i = 0; i < 8; i++)
#pragma unroll
                for (int j = 0; j < 8; j++)
                    acc[i][j] = fmaf(a[i], b[j], acc[i][j]);
        }
        __syncthreads();
    }
    // epilogue: bias, exp-sum per row, picked logit
    int yreg[8];
#pragma unroll
    for (int i = 0; i < 8; i++) {
        int rl = (i < 4) ? ty * 4 + i : 64 + ty * 4 + (i - 4);
        yreg[i] = y[rowBase + rl];
    }
    float rsum[8] = {0.f, 0.f, 0.f, 0.f, 0.f, 0.f, 0.f, 0.f};
#pragma unroll
    for (int j = 0; j < 8; j++) {
        int cl = (j < 4) ? tx * 4 + j : 64 + tx * 4 + (j - 4);
        int v = colBase + cl;
        float bd = b_dec[v];
#pragma unroll
        for (int i = 0; i < 8; i++) {
            float logit = acc[i][j] + bd;
            rsum[i] += __expf(logit);
            if (v == yreg[i]) {
                int rl = (i < 4) ? ty * 4 + i : 64 + ty * 4 + (i - 4);
                picked[rowBase + rl] = logit;
            }
        }
    }
    // cross-tx reduction of per-row partial sums (reuse As as scratch)
    float* red = &As[0][0];
#pragma unroll
    for (int i = 0; i < 8; i++) {
        int rl = (i < 4) ? ty * 4 + i : 64 + ty * 4 + (i - 4);
        red[rl * 16 + tx] = rsum[i];
    }
    __syncthreads();
    if (tid < 128) {
        float s = 0.f;
#pragma unroll
        for (int m = 0; m < 16; m++) s += red[tid * 16 + m];
        atomicAdd(&sumexp[rowBase + tid], s);
    }
}

// ---------------------------------------------------------------------------
// K4: loss[b] = -sum_t (picked[b*T+t] - log(sumexp[b*T+t]))
// ---------------------------------------------------------------------------
__global__ void loss_kernel(const float* __restrict__ picked,
                            const float* __restrict__ sumexp,
                            float* __restrict__ out) {
    int b = threadIdx.x;
    if (b >= NB) return;
    float s = 0.f;
    for (int t = 0; t < NT; t++) {
        int r = b * NT + t;
        s += picked[r] - logf(sumexp[r]);
    }
    out[b] = -s;
}

// ---------------------------------------------------------------------------
extern "C" void kernel_launch(void* const* d_in, const int* in_sizes, int n_in,
                              void* d_out, int out_size, void* d_ws, size_t ws_size,
                              hipStream_t stream) {
    const int*   x     = (const int*)d_in[0];
    const int*   y     = (const int*)d_in[1];
    const float* ctx   = (const float*)d_in[2];
    const float* emb   = (const float*)d_in[3];
    const float* W_ih  = (const float*)d_in[4];
    const float* W_hh  = (const float*)d_in[5];
    const float* b_ih  = (const float*)d_in[6];
    const float* b_hh  = (const float*)d_in[7];
    const float* W_dec = (const float*)d_in[8];
    const float* b_dec = (const float*)d_in[9];
    float* out = (float*)d_out;

    // workspace carve (floats)
    float* ws     = (float*)d_ws;
    float* inp    = ws;                        // 8192*384   = 3,145,728
    float* xg     = inp + (size_t)BT * ECK;    // 8192*2048  = 16,777,216
    float* hs     = xg + (size_t)BT * G4;      // 8192*512   = 4,194,304
    float* hbuf   = hs + (size_t)BT * NH;      // 2 * 65536
    float* cbuf   = hbuf + 2 * NB * NH;        // 2 * 65536
    float* sumexp = cbuf + 2 * NB * NH;        // 8192
    float* picked = sumexp + BT;               // 8192

    hipMemsetAsync(hbuf, 0, NB * NH * sizeof(float), stream);
    hipMemsetAsync(cbuf, 0, NB * NH * sizeof(float), stream);
    hipMemsetAsync(sumexp, 0, BT * sizeof(float), stream);

    build_inp<<<(BT * (ECK / 4) + 255) / 256, 256, 0, stream>>>(x, ctx, emb, inp);

    gemm_xg<<<dim3(G4 / 128, BT / 128), 256, 0, stream>>>(inp, W_ih, b_ih, b_hh, xg);

    for (int t = 0; t < NT; t++) {
        const float* hp = hbuf + (t & 1) * NB * NH;
        float*       hn = hbuf + ((t + 1) & 1) * NB * NH;
        const float* cp = cbuf + (t & 1) * NB * NH;
        float*       cn = cbuf + ((t + 1) & 1) * NB * NH;
        lstm_step<<<dim3(NH / 16, NB / 32), 256, 0, stream>>>(
            hp, cp, xg, W_hh, hn, cn, hs, t);
    }

    decoder_lse<<<dim3(NV / 128, BT / 128), 256, 0, stream>>>(
        hs, W_dec, b_dec, y, sumexp, picked);

    loss_kernel<<<1, 128, 0, stream>>>(picked, sumexp, out);
}

// Round 2
// 1908.892 us; speedup vs baseline: 1.6441x; 1.6441x over previous
//
#include <hip/hip_runtime.h>
#include <cmath>

// Problem constants
#define NB   128      // batch
#define NT   64       // time
#define NV   16000    // vocab
#define NE   128      // emb dim
#define NC   256      // context dim
#define NH   512      // hidden
#define G4   2048     // 4*NH
#define ECK  384      // NE+NC
#define BT   8192     // NB*NT

typedef __attribute__((ext_vector_type(8))) short bf16x8;
typedef __attribute__((ext_vector_type(4))) float f32x4;
typedef const void __attribute__((address_space(1)))* gptr_t;
typedef void __attribute__((address_space(3)))* sptr_t;

static __device__ __forceinline__ unsigned short f2bf(float f) {
    union { float f; unsigned u; } a; a.f = f;
    unsigned r = (a.u + 0x7fff + ((a.u >> 16) & 1)) >> 16;   // RNE
    return (unsigned short)r;
}

// ---------------------------------------------------------------------------
// K0: build inp[t*128+b][384] = concat(emb_table[x[b][t]], context[b])
// ---------------------------------------------------------------------------
__global__ void build_inp(const int* __restrict__ x, const float* __restrict__ ctx,
                          const float* __restrict__ emb, float* __restrict__ inp) {
    int f = blockIdx.x * blockDim.x + threadIdx.x;   // float4 index
    const int total = BT * (ECK / 4);
    if (f >= total) return;
    int row = f / (ECK / 4);
    int c4  = f % (ECK / 4);
    int b = row & (NB - 1);
    int c = c4 * 4;
    float4 v;
    if (c < NE) {
        int t = row >> 7;
        int tok = x[b * NT + t];
        v = *(const float4*)(emb + tok * NE + c);
    } else {
        v = *(const float4*)(ctx + b * NC + (c - NE));
    }
    ((float4*)inp)[f] = v;
}

// ---------------------------------------------------------------------------
// K0b: fp32 -> bf16 convert (for W_dec), float4 / ushort4 vectorized
// ---------------------------------------------------------------------------
__global__ void f32_to_bf16(const float* __restrict__ src, unsigned short* __restrict__ dst, int n4) {
    int i = blockIdx.x * blockDim.x + threadIdx.x;
    if (i >= n4) return;
    float4 v = ((const float4*)src)[i];
    ushort4 o;
    o.x = f2bf(v.x); o.y = f2bf(v.y); o.z = f2bf(v.z); o.w = f2bf(v.w);
    ((ushort4*)dst)[i] = o;
}

// ---------------------------------------------------------------------------
// K1: xg[row=(t*128+b)][j] = inp[row]·W_ih[j] + b_ih[j] + b_hh[j]   (fp32)
// ---------------------------------------------------------------------------
#define KC 32
#define LDL 132

__global__ __launch_bounds__(256, 2) void gemm_xg(
    const float* __restrict__ A,    // inp [BT][384]
    const float* __restrict__ Bw,   // W_ih [2048][384]
    const float* __restrict__ b_ih, const float* __restrict__ b_hh,
    float* __restrict__ xg)         // [BT][2048]
{
    __shared__ float As[KC][LDL];
    __shared__ float Bs[KC][LDL];
    const int tid = threadIdx.x;
    const int tx = tid & 15, ty = tid >> 4;
    const int rowBase = blockIdx.y * 128;
    const int colBase = blockIdx.x * 128;
    float acc[8][8];
#pragma unroll
    for (int i = 0; i < 8; i++)
#pragma unroll
        for (int j = 0; j < 8; j++) acc[i][j] = 0.f;

    for (int kb = 0; kb < ECK; kb += KC) {
#pragma unroll
        for (int l = 0; l < 4; ++l) {
            int f4 = tid + l * 256;
            int r = f4 >> 3, kq = f4 & 7;
            float4 v = *(const float4*)(A + (rowBase + r) * ECK + kb + kq * 4);
            As[kq * 4 + 0][r] = v.x; As[kq * 4 + 1][r] = v.y;
            As[kq * 4 + 2][r] = v.z; As[kq * 4 + 3][r] = v.w;
        }
#pragma unroll
        for (int l = 0; l < 4; ++l) {
            int f4 = tid + l * 256;
            int r = f4 >> 3, kq = f4 & 7;
            float4 v = *(const float4*)(Bw + (colBase + r) * ECK + kb + kq * 4);
            Bs[kq * 4 + 0][r] = v.x; Bs[kq * 4 + 1][r] = v.y;
            Bs[kq * 4 + 2][r] = v.z; Bs[kq * 4 + 3][r] = v.w;
        }
        __syncthreads();
#pragma unroll
        for (int k = 0; k < KC; ++k) {
            float a[8], b[8];
            *(float4*)&a[0] = *(const float4*)&As[k][ty * 4];
            *(float4*)&a[4] = *(const float4*)&As[k][64 + ty * 4];
            *(float4*)&b[0] = *(const float4*)&Bs[k][tx * 4];
            *(float4*)&b[4] = *(const float4*)&Bs[k][64 + tx * 4];
#pragma unroll
            for (int i = 0; i < 8; i++)
#pragma unroll
                for (int j = 0; j < 8; j++)
                    acc[i][j] = fmaf(a[i], b[j], acc[i][j]);
        }
        __syncthreads();
    }
    float bias[8];
#pragma unroll
    for (int j = 0; j < 8; j++) {
        int col = colBase + ((j < 4) ? tx * 4 + j : 64 + tx * 4 + (j - 4));
        bias[j] = b_ih[col] + b_hh[col];
    }
#pragma unroll
    for (int i = 0; i < 8; i++) {
        int row = rowBase + ((i < 4) ? ty * 4 + i : 64 + ty * 4 + (i - 4));
        float4 lo = { acc[i][0] + bias[0], acc[i][1] + bias[1],
                      acc[i][2] + bias[2], acc[i][3] + bias[3] };
        float4 hi = { acc[i][4] + bias[4], acc[i][5] + bias[5],
                      acc[i][6] + bias[6], acc[i][7] + bias[7] };
        *(float4*)(xg + row * G4 + colBase + tx * 4)      = lo;
        *(float4*)(xg + row * G4 + colBase + 64 + tx * 4) = hi;
    }
}

// ---------------------------------------------------------------------------
// K2: one LSTM step (fp32). Emits h as bf16 into hs_bf (decoder A-matrix).
// ---------------------------------------------------------------------------
#define SKC 128
__global__ __launch_bounds__(256, 2) void lstm_step(
    const float* __restrict__ h_prev, const float* __restrict__ c_prev,
    const float* __restrict__ xg, const float* __restrict__ W_hh,
    float* __restrict__ h_next, float* __restrict__ c_next,
    unsigned short* __restrict__ hs_bf, int t)
{
    __shared__ float As[SKC][34];   // h_prev chunk, transposed [k][b]
    __shared__ float Bs[SKC][68];   // W rows chunk, transposed [k][c]
    const int tid = threadIdx.x;
    const int tx = tid & 15, ty = tid >> 4;
    const int hBase = blockIdx.x * 16;
    const int bBase = blockIdx.y * 32;
    float acc[2][4];
#pragma unroll
    for (int e = 0; e < 2; e++)
#pragma unroll
        for (int g = 0; g < 4; g++) acc[e][g] = 0.f;

    for (int kb = 0; kb < NH; kb += SKC) {
#pragma unroll
        for (int l = 0; l < 4; ++l) {
            int f4 = tid + l * 256;
            int r = f4 >> 5, kq = f4 & 31;
            float4 v = *(const float4*)(h_prev + (bBase + r) * NH + kb + kq * 4);
            As[kq * 4 + 0][r] = v.x; As[kq * 4 + 1][r] = v.y;
            As[kq * 4 + 2][r] = v.z; As[kq * 4 + 3][r] = v.w;
        }
#pragma unroll
        for (int l = 0; l < 8; ++l) {
            int f4 = tid + l * 256;
            int c = f4 >> 5, kq = f4 & 31;
            int wrow = (c & 3) * NH + hBase + (c >> 2);
            float4 v = *(const float4*)(W_hh + wrow * NH + kb + kq * 4);
            Bs[kq * 4 + 0][c] = v.x; Bs[kq * 4 + 1][c] = v.y;
            Bs[kq * 4 + 2][c] = v.z; Bs[kq * 4 + 3][c] = v.w;
        }
        __syncthreads();
#pragma unroll
        for (int k = 0; k < SKC; ++k) {
            float2 a = *(const float2*)&As[k][ty * 2];
            float4 b = *(const float4*)&Bs[k][tx * 4];
            acc[0][0] = fmaf(a.x, b.x, acc[0][0]);
            acc[0][1] = fmaf(a.x, b.y, acc[0][1]);
            acc[0][2] = fmaf(a.x, b.z, acc[0][2]);
            acc[0][3] = fmaf(a.x, b.w, acc[0][3]);
            acc[1][0] = fmaf(a.y, b.x, acc[1][0]);
            acc[1][1] = fmaf(a.y, b.y, acc[1][1]);
            acc[1][2] = fmaf(a.y, b.z, acc[1][2]);
            acc[1][3] = fmaf(a.y, b.w, acc[1][3]);
        }
        __syncthreads();
    }
    const int h = hBase + tx;
#pragma unroll
    for (int e = 0; e < 2; e++) {
        int b = bBase + ty * 2 + e;
        const float* xgr = xg + (t * NB + b) * G4;
        float gi = acc[e][0] + xgr[h];
        float gf = acc[e][1] + xgr[NH + h];
        float gg = acc[e][2] + xgr[2 * NH + h];
        float go = acc[e][3] + xgr[3 * NH + h];
        float i_ = 1.f / (1.f + __expf(-gi));
        float f_ = 1.f / (1.f + __expf(-gf));
        float o_ = 1.f / (1.f + __expf(-go));
        float cp = c_prev[b * NH + h];
        float cn = f_ * cp + i_ * tanhf(gg);
        float hn = o_ * tanhf(cn);
        c_next[b * NH + h] = cn;
        h_next[b * NH + h] = hn;
        hs_bf[(size_t)(b * NT + t) * NH + h] = f2bf(hn);   // decoder rows: b*T+t
    }
}

// ---------------------------------------------------------------------------
// K3: decoder GEMM (bf16 MFMA) + fused log-sum-exp.
// m97 structure: 128x128 tile, 4 waves (2x2), BK=64, global_load_lds w=16,
// XOR-swizzled LDS chunks (chunk ^= row&7) via pre-swizzled global source.
// Logits are tiny (|logit| < ~4): LSE needs no max subtraction.
// ---------------------------------------------------------------------------
__global__ __launch_bounds__(256, 2) void decoder_mfma(
    const unsigned short* __restrict__ A,   // hs_bf [BT][512]
    const unsigned short* __restrict__ Bw,  // W_dec_bf [16000][512]
    const float* __restrict__ b_dec,
    const int* __restrict__ y,              // flat, row index == b*T+t
    float* __restrict__ sumexp,             // [BT], pre-zeroed
    float* __restrict__ picked)             // [BT]
{
    __shared__ short As[128 * 64];   // 16 KB, row-major [row][64k], 16B-chunk-swizzled
    __shared__ short Bs[128 * 64];   // 16 KB
    const int tid  = threadIdx.x;
    const int lane = tid & 63;
    const int wv   = tid >> 6;            // 4 waves
    const int wr   = wv >> 1, wc = wv & 1;  // 2x2 wave grid, 64x64 out each
    const int rowBase = blockIdx.y * 128;
    const int colBase = blockIdx.x * 128;

    f32x4 acc[4][4];
#pragma unroll
    for (int m = 0; m < 4; m++)
#pragma unroll
        for (int n = 0; n < 4; n++) acc[m][n] = (f32x4){0.f, 0.f, 0.f, 0.f};

    for (int kb = 0; kb < NH; kb += 64) {
#pragma unroll
        for (int i = 0; i < 4; ++i) {
            int f = tid + i * 256;          // 16B chunk index, 0..1023
            int r = f >> 3, pc = f & 7;
            int lc = pc ^ (r & 7);          // pre-swizzle the SOURCE (dest is linear)
            const unsigned short* srcA = A  + (size_t)(rowBase + r) * NH + kb + lc * 8;
            const unsigned short* srcB = Bw + (size_t)(colBase + r) * NH + kb + lc * 8;
            __builtin_amdgcn_global_load_lds((gptr_t)srcA, (sptr_t)(As + f * 8), 16, 0, 0);
            __builtin_amdgcn_global_load_lds((gptr_t)srcB, (sptr_t)(Bs + f * 8), 16, 0, 0);
        }
        __syncthreads();   // drains vmcnt before barrier (compiler-enforced)
#pragma unroll
        for (int kk = 0; kk < 2; ++kk) {
            bf16x8 af[4], bfr[4];
#pragma unroll
            for (int m = 0; m < 4; ++m) {
                int r  = wr * 64 + m * 16 + (lane & 15);
                int pc = (kk * 4 + (lane >> 4)) ^ (r & 7);
                af[m] = *(const bf16x8*)(As + r * 64 + pc * 8);
            }
#pragma unroll
            for (int n = 0; n < 4; ++n) {
                int r  = wc * 64 + n * 16 + (lane & 15);
                int pc = (kk * 4 + (lane >> 4)) ^ (r & 7);
                bfr[n] = *(const bf16x8*)(Bs + r * 64 + pc * 8);
            }
#pragma unroll
            for (int m = 0; m < 4; ++m)
#pragma unroll
                for (int n = 0; n < 4; ++n)
                    acc[m][n] = __builtin_amdgcn_mfma_f32_16x16x32_bf16(af[m], bfr[n], acc[m][n], 0, 0, 0);
        }
        __syncthreads();
    }

    // Epilogue: C row = rBase + m*16 + (lane>>4)*4 + reg ; col = cBase + n*16 + (lane&15)
    const int rBase = rowBase + wr * 64;
    const int cBase = colBase + wc * 64;
    int   yv[4][4];
#pragma unroll
    for (int m = 0; m < 4; ++m)
#pragma unroll
        for (int reg = 0; reg < 4; ++reg)
            yv[m][reg] = y[rBase + m * 16 + (lane >> 4) * 4 + reg];

    float rs[4][4];
#pragma unroll
    for (int m = 0; m < 4; ++m)
#pragma unroll
        for (int reg = 0; reg < 4; ++reg) rs[m][reg] = 0.f;

#pragma unroll
    for (int n = 0; n < 4; ++n) {
        int v = cBase + n * 16 + (lane & 15);
        float bd = b_dec[v];
#pragma unroll
        for (int m = 0; m < 4; ++m)
#pragma unroll
            for (int reg = 0; reg < 4; ++reg) {
                float logit = acc[m][n][reg] + bd;
                if (v == yv[m][reg])
                    picked[rBase + m * 16 + (lane >> 4) * 4 + reg] = logit;
                rs[m][reg] += __expf(logit);
            }
    }
    // reduce across the 16 lanes sharing a row (lane&15), then 1 atomic / row-half
#pragma unroll
    for (int m = 0; m < 4; ++m)
#pragma unroll
        for (int reg = 0; reg < 4; ++reg) {
            float s = rs[m][reg];
            s += __shfl_xor(s, 1);
            s += __shfl_xor(s, 2);
            s += __shfl_xor(s, 4);
            s += __shfl_xor(s, 8);
            if ((lane & 15) == 0)
                atomicAdd(&sumexp[rBase + m * 16 + (lane >> 4) * 4 + reg], s);
        }
}

// ---------------------------------------------------------------------------
// K4: loss[b] = -sum_t (picked[b*T+t] - log(sumexp[b*T+t]))
// ---------------------------------------------------------------------------
__global__ void loss_kernel(const float* __restrict__ picked,
                            const float* __restrict__ sumexp,
                            float* __restrict__ out) {
    int b = threadIdx.x;
    if (b >= NB) return;
    float s = 0.f;
    for (int t = 0; t < NT; t++) {
        int r = b * NT + t;
        s += picked[r] - logf(sumexp[r]);
    }
    out[b] = -s;
}

// ---------------------------------------------------------------------------
extern "C" void kernel_launch(void* const* d_in, const int* in_sizes, int n_in,
                              void* d_out, int out_size, void* d_ws, size_t ws_size,
                              hipStream_t stream) {
    const int*   x     = (const int*)d_in[0];
    const int*   y     = (const int*)d_in[1];
    const float* ctx   = (const float*)d_in[2];
    const float* emb   = (const float*)d_in[3];
    const float* W_ih  = (const float*)d_in[4];
    const float* W_hh  = (const float*)d_in[5];
    const float* b_ih  = (const float*)d_in[6];
    const float* b_hh  = (const float*)d_in[7];
    const float* W_dec = (const float*)d_in[8];
    const float* b_dec = (const float*)d_in[9];
    float* out = (float*)d_out;

    // workspace carve
    float*          ws      = (float*)d_ws;
    float*          inp     = ws;                         // 8192*384 f32
    float*          xg      = inp + (size_t)BT * ECK;     // 8192*2048 f32
    float*          hbuf    = xg + (size_t)BT * G4;       // 2 * 128*512 f32
    float*          cbuf    = hbuf + 2 * NB * NH;         // 2 * 128*512 f32
    float*          sumexp  = cbuf + 2 * NB * NH;         // 8192 f32
    float*          picked  = sumexp + BT;                // 8192 f32
    unsigned short* hs_bf   = (unsigned short*)(picked + BT);          // 8192*512 bf16
    unsigned short* wdec_bf = hs_bf + (size_t)BT * NH;                 // 16000*512 bf16

    hipMemsetAsync(hbuf, 0, NB * NH * sizeof(float), stream);
    hipMemsetAsync(cbuf, 0, NB * NH * sizeof(float), stream);
    hipMemsetAsync(sumexp, 0, BT * sizeof(float), stream);

    f32_to_bf16<<<(NV * NH / 4 + 255) / 256, 256, 0, stream>>>(W_dec, wdec_bf, NV * NH / 4);

    build_inp<<<(BT * (ECK / 4) + 255) / 256, 256, 0, stream>>>(x, ctx, emb, inp);

    gemm_xg<<<dim3(G4 / 128, BT / 128), 256, 0, stream>>>(inp, W_ih, b_ih, b_hh, xg);

    for (int t = 0; t < NT; t++) {
        const float* hp = hbuf + (t & 1) * NB * NH;
        float*       hn = hbuf + ((t + 1) & 1) * NB * NH;
        const float* cp = cbuf + (t & 1) * NB * NH;
        float*       cn = cbuf + ((t + 1) & 1) * NB * NH;
        lstm_step<<<dim3(NH / 16, NB / 32), 256, 0, stream>>>(
            hp, cp, xg, W_hh, hn, cn, hs_bf, t);
    }

    decoder_mfma<<<dim3(NV / 128, BT / 128), 256, 0, stream>>>(
        hs_bf, wdec_bf, b_dec, y, sumexp, picked);

    loss_kernel<<<1, 128, 0, stream>>>(picked, sumexp, out);
}

// Round 3
// 1428.348 us; speedup vs baseline: 2.1972x; 1.3364x over previous
//
#include <hip/hip_runtime.h>
#include <cmath>

// Problem constants
#define NB   128      // batch
#define NT   64       // time
#define NV   16000    // vocab
#define NE   128      // emb dim
#define NC   256      // context dim
#define NH   512      // hidden
#define G4   2048     // 4*NH
#define ECK  384      // NE+NC
#define BT   8192     // NB*NT

typedef __attribute__((ext_vector_type(8))) short bf16x8;
typedef __attribute__((ext_vector_type(4))) float f32x4;
typedef const void __attribute__((address_space(1)))* gptr_t;
typedef void __attribute__((address_space(3)))* sptr_t;

static __device__ __forceinline__ unsigned short f2bf(float f) {
    union { float f; unsigned u; } a; a.f = f;
    unsigned r = (a.u + 0x7fff + ((a.u >> 16) & 1)) >> 16;   // RNE
    return (unsigned short)r;
}

// ---------------------------------------------------------------------------
// K0: build inp_bf[t*128+b][384] = bf16(concat(emb_table[x[b][t]], context[b]))
// ---------------------------------------------------------------------------
__global__ void build_inp_bf(const int* __restrict__ x, const float* __restrict__ ctx,
                             const float* __restrict__ emb, unsigned short* __restrict__ inp) {
    int f = blockIdx.x * blockDim.x + threadIdx.x;   // float4 index
    const int total = BT * (ECK / 4);
    if (f >= total) return;
    int row = f / (ECK / 4);
    int c4  = f % (ECK / 4);
    int b = row & (NB - 1);
    int c = c4 * 4;
    float4 v;
    if (c < NE) {
        int t = row >> 7;
        int tok = x[b * NT + t];
        v = *(const float4*)(emb + tok * NE + c);
    } else {
        v = *(const float4*)(ctx + b * NC + (c - NE));
    }
    ushort4 o;
    o.x = f2bf(v.x); o.y = f2bf(v.y); o.z = f2bf(v.z); o.w = f2bf(v.w);
    ((ushort4*)inp)[f] = o;
}

// ---------------------------------------------------------------------------
// K0b: fp32 -> bf16 convert (W_dec, W_hh, W_ih)
// ---------------------------------------------------------------------------
__global__ void f32_to_bf16(const float* __restrict__ src, unsigned short* __restrict__ dst, int n4) {
    int i = blockIdx.x * blockDim.x + threadIdx.x;
    if (i >= n4) return;
    float4 v = ((const float4*)src)[i];
    ushort4 o;
    o.x = f2bf(v.x); o.y = f2bf(v.y); o.z = f2bf(v.z); o.w = f2bf(v.w);
    ((ushort4*)dst)[i] = o;
}

// ---------------------------------------------------------------------------
// K1: xg = inp_bf @ W_ih^T + b_ih + b_hh  (bf16 MFMA, m97 structure, K=384)
// 128x128 tile, 4 waves (2x2), BK=64, global_load_lds w=16, XOR-swizzled LDS.
// ---------------------------------------------------------------------------
__global__ __launch_bounds__(256, 2) void gemm_xg_bf(
    const unsigned short* __restrict__ A,   // inp_bf [BT][384]
    const unsigned short* __restrict__ Bw,  // wih_bf [2048][384]
    const float* __restrict__ b_ih, const float* __restrict__ b_hh,
    float* __restrict__ xg)                 // [BT][2048] f32
{
    __shared__ short As[128 * 64];
    __shared__ short Bs[128 * 64];
    const int tid  = threadIdx.x;
    const int lane = tid & 63;
    const int wv   = tid >> 6;
    const int wr   = wv >> 1, wc = wv & 1;
    const int rowBase = blockIdx.y * 128;
    const int colBase = blockIdx.x * 128;

    f32x4 acc[4][4];
#pragma unroll
    for (int m = 0; m < 4; m++)
#pragma unroll
        for (int n = 0; n < 4; n++) acc[m][n] = (f32x4){0.f, 0.f, 0.f, 0.f};

    for (int kb = 0; kb < ECK; kb += 64) {
#pragma unroll
        for (int i = 0; i < 4; ++i) {
            int f = tid + i * 256;
            int r = f >> 3, pc = f & 7;
            int lc = pc ^ (r & 7);
            const unsigned short* srcA = A  + (size_t)(rowBase + r) * ECK + kb + lc * 8;
            const unsigned short* srcB = Bw + (size_t)(colBase + r) * ECK + kb + lc * 8;
            __builtin_amdgcn_global_load_lds((gptr_t)srcA, (sptr_t)(As + f * 8), 16, 0, 0);
            __builtin_amdgcn_global_load_lds((gptr_t)srcB, (sptr_t)(Bs + f * 8), 16, 0, 0);
        }
        __syncthreads();
#pragma unroll
        for (int kk = 0; kk < 2; ++kk) {
            bf16x8 af[4], bfr[4];
#pragma unroll
            for (int m = 0; m < 4; ++m) {
                int r  = wr * 64 + m * 16 + (lane & 15);
                int pc = (kk * 4 + (lane >> 4)) ^ (r & 7);
                af[m] = *(const bf16x8*)(As + r * 64 + pc * 8);
            }
#pragma unroll
            for (int n = 0; n < 4; ++n) {
                int r  = wc * 64 + n * 16 + (lane & 15);
                int pc = (kk * 4 + (lane >> 4)) ^ (r & 7);
                bfr[n] = *(const bf16x8*)(Bs + r * 64 + pc * 8);
            }
#pragma unroll
            for (int m = 0; m < 4; ++m)
#pragma unroll
                for (int n = 0; n < 4; ++n)
                    acc[m][n] = __builtin_amdgcn_mfma_f32_16x16x32_bf16(af[m], bfr[n], acc[m][n], 0, 0, 0);
        }
        __syncthreads();
    }
    const int rBase = rowBase + wr * 64;
    const int cBase = colBase + wc * 64;
#pragma unroll
    for (int n = 0; n < 4; ++n) {
        int col = cBase + n * 16 + (lane & 15);
        float bias = b_ih[col] + b_hh[col];
#pragma unroll
        for (int m = 0; m < 4; ++m)
#pragma unroll
            for (int reg = 0; reg < 4; ++reg) {
                int row = rBase + m * 16 + (lane >> 4) * 4 + reg;
                xg[(size_t)row * G4 + col] = acc[m][n][reg] + bias;
            }
    }
}

// ---------------------------------------------------------------------------
// K2: persistent LSTM — all 64 timesteps in one kernel.
// Grid (32 hb, 8 bb) = 256 blocks (1/CU via LDS), 256 threads (4 waves).
// Block owns a (16 batch x 16 h) patch; W_hh slice (64 rows) lives in LDS.
// Per step: group barrier (32 blocks sharing batches) -> stage h panel ->
// 16 MFMA/wave -> gates -> h stores (bf16). c-state persistent in LDS.
// ---------------------------------------------------------------------------
__global__ __launch_bounds__(256, 1) void lstm_persistent(
    const unsigned short* __restrict__ whh_bf,   // [2048][512] bf16
    const float* __restrict__ xg,                // [BT][2048] f32, row t*128+b
    unsigned short* __restrict__ h_bf,           // [2][128][512] bf16 (buf0 zeroed)
    unsigned short* __restrict__ hs_bf,          // [8192][512] bf16, row b*64+t
    unsigned int* __restrict__ bar)              // [64][8] zeroed
{
    __shared__ short Ws[64 * 512];     // 64 KB W_hh slice (rows c=g*16+j)
    __shared__ short As[16 * 512];     // 16 KB staged h panel
    __shared__ float Cs[16][64];       // C scratch
    __shared__ float cst[16 * 16];     // persistent c state
    const int tid  = threadIdx.x;
    const int lane = tid & 63;
    const int wv   = tid >> 6;
    const int hb = blockIdx.x, bb = blockIdx.y;
    const int hBase = hb * 16;
    const int bBase = bb * 16;

    // stage W slice once; LDS[r][ch] = whh[wrow(r)][ch ^ (r&7)]
#pragma unroll
    for (int i = 0; i < 16; ++i) {
        int f = tid + i * 256;
        int r = f >> 6, ch = f & 63;
        int g = r >> 4, j = r & 15;
        const unsigned short* src = whh_bf + (size_t)((g << 9) + hBase + j) * NH + ((ch ^ (r & 7)) << 3);
        __builtin_amdgcn_global_load_lds((gptr_t)src, (sptr_t)(Ws + f * 8), 16, 0, 0);
    }
    cst[tid & 255] = 0.f;
    __syncthreads();

#pragma unroll 1
    for (int t = 0; t < NT; ++t) {
        if (t > 0) {
            if (tid == 0) {
                while (__hip_atomic_load(&bar[(t - 1) * 8 + bb], __ATOMIC_RELAXED,
                                         __HIP_MEMORY_SCOPE_AGENT) < 32u)
                    __builtin_amdgcn_s_sleep(2);
                __builtin_amdgcn_fence(__ATOMIC_ACQUIRE, "agent");   // inv L1/L2: fresh h panel
            }
            __syncthreads();
        }
        // stage h[bBase..bBase+15][0..511] from h_bf[t&1], swizzled source
        const unsigned short* hsrc = h_bf + (size_t)(t & 1) * NB * NH;
#pragma unroll
        for (int i = 0; i < 4; ++i) {
            int f = tid + i * 256;
            int r = f >> 6, ch = f & 63;
            const unsigned short* src = hsrc + (size_t)(bBase + r) * NH + ((ch ^ (r & 7)) << 3);
            __builtin_amdgcn_global_load_lds((gptr_t)src, (sptr_t)(As + f * 8), 16, 0, 0);
        }
        __syncthreads();

        // C[16][64] = h(16x512) @ Ws(64x512)^T ; wave wv owns n-tile wv
        f32x4 acc = (f32x4){0.f, 0.f, 0.f, 0.f};
        const int ar = lane & 15;
        const int br = wv * 16 + (lane & 15);
#pragma unroll
        for (int kc = 0; kc < 16; ++kc) {
            int cA = (kc * 4 + (lane >> 4)) ^ (ar & 7);
            int cB = (kc * 4 + (lane >> 4)) ^ (br & 7);
            bf16x8 a = *(const bf16x8*)(As + ar * 512 + cA * 8);
            bf16x8 b = *(const bf16x8*)(Ws + br * 512 + cB * 8);
            acc = __builtin_amdgcn_mfma_f32_16x16x32_bf16(a, b, acc, 0, 0, 0);
        }
#pragma unroll
        for (int reg = 0; reg < 4; ++reg)
            Cs[(lane >> 4) * 4 + reg][wv * 16 + (lane & 15)] = acc[reg];
        __syncthreads();

        // gates: thread -> (b = tid>>4, j = tid&15)
        {
            int b = tid >> 4, j = tid & 15;
            int hAbs = hBase + j;
            const float* xgr = xg + (size_t)(t * NB + bBase + b) * G4;
            float gi = Cs[b][j]      + xgr[hAbs];
            float gf = Cs[b][16 + j] + xgr[NH + hAbs];
            float gg = Cs[b][32 + j] + xgr[2 * NH + hAbs];
            float go = Cs[b][48 + j] + xgr[3 * NH + hAbs];
            float i_ = 1.f / (1.f + __expf(-gi));
            float f_ = 1.f / (1.f + __expf(-gf));
            float o_ = 1.f / (1.f + __expf(-go));
            float cp = cst[tid];
            float cn = f_ * cp + i_ * tanhf(gg);
            float hn = o_ * tanhf(cn);
            cst[tid] = cn;
            unsigned short h16 = f2bf(hn);
            h_bf[(size_t)((t + 1) & 1) * NB * NH + (size_t)(bBase + b) * NH + hAbs] = h16;
            hs_bf[((size_t)(bBase + b) * NT + t) * NH + hAbs] = h16;
        }
        if (t < NT - 1) {
            __syncthreads();   // drains vmcnt: all block h-stores issued to L2
            if (tid == 0) {
                __builtin_amdgcn_fence(__ATOMIC_RELEASE, "agent");   // wb L2 -> visible cross-XCD
                __hip_atomic_fetch_add(&bar[t * 8 + bb], 1u, __ATOMIC_RELAXED,
                                       __HIP_MEMORY_SCOPE_AGENT);
            }
        }
    }
}

// ---------------------------------------------------------------------------
// K3: decoder GEMM (bf16 MFMA) + fused log-sum-exp. (unchanged from round 2)
// ---------------------------------------------------------------------------
__global__ __launch_bounds__(256, 2) void decoder_mfma(
    const unsigned short* __restrict__ A,   // hs_bf [BT][512]
    const unsigned short* __restrict__ Bw,  // W_dec_bf [16000][512]
    const float* __restrict__ b_dec,
    const int* __restrict__ y,
    float* __restrict__ sumexp,
    float* __restrict__ picked)
{
    __shared__ short As[128 * 64];
    __shared__ short Bs[128 * 64];
    const int tid  = threadIdx.x;
    const int lane = tid & 63;
    const int wv   = tid >> 6;
    const int wr   = wv >> 1, wc = wv & 1;
    const int rowBase = blockIdx.y * 128;
    const int colBase = blockIdx.x * 128;

    f32x4 acc[4][4];
#pragma unroll
    for (int m = 0; m < 4; m++)
#pragma unroll
        for (int n = 0; n < 4; n++) acc[m][n] = (f32x4){0.f, 0.f, 0.f, 0.f};

    for (int kb = 0; kb < NH; kb += 64) {
#pragma unroll
        for (int i = 0; i < 4; ++i) {
            int f = tid + i * 256;
            int r = f >> 3, pc = f & 7;
            int lc = pc ^ (r & 7);
            const unsigned short* srcA = A  + (size_t)(rowBase + r) * NH + kb + lc * 8;
            const unsigned short* srcB = Bw + (size_t)(colBase + r) * NH + kb + lc * 8;
            __builtin_amdgcn_global_load_lds((gptr_t)srcA, (sptr_t)(As + f * 8), 16, 0, 0);
            __builtin_amdgcn_global_load_lds((gptr_t)srcB, (sptr_t)(Bs + f * 8), 16, 0, 0);
        }
        __syncthreads();
#pragma unroll
        for (int kk = 0; kk < 2; ++kk) {
            bf16x8 af[4], bfr[4];
#pragma unroll
            for (int m = 0; m < 4; ++m) {
                int r  = wr * 64 + m * 16 + (lane & 15);
                int pc = (kk * 4 + (lane >> 4)) ^ (r & 7);
                af[m] = *(const bf16x8*)(As + r * 64 + pc * 8);
            }
#pragma unroll
            for (int n = 0; n < 4; ++n) {
                int r  = wc * 64 + n * 16 + (lane & 15);
                int pc = (kk * 4 + (lane >> 4)) ^ (r & 7);
                bfr[n] = *(const bf16x8*)(Bs + r * 64 + pc * 8);
            }
#pragma unroll
            for (int m = 0; m < 4; ++m)
#pragma unroll
                for (int n = 0; n < 4; ++n)
                    acc[m][n] = __builtin_amdgcn_mfma_f32_16x16x32_bf16(af[m], bfr[n], acc[m][n], 0, 0, 0);
        }
        __syncthreads();
    }

    const int rBase = rowBase + wr * 64;
    const int cBase = colBase + wc * 64;
    int yv[4][4];
#pragma unroll
    for (int m = 0; m < 4; ++m)
#pragma unroll
        for (int reg = 0; reg < 4; ++reg)
            yv[m][reg] = y[rBase + m * 16 + (lane >> 4) * 4 + reg];

    float rs[4][4];
#pragma unroll
    for (int m = 0; m < 4; ++m)
#pragma unroll
        for (int reg = 0; reg < 4; ++reg) rs[m][reg] = 0.f;

#pragma unroll
    for (int n = 0; n < 4; ++n) {
        int v = cBase + n * 16 + (lane & 15);
        float bd = b_dec[v];
#pragma unroll
        for (int m = 0; m < 4; ++m)
#pragma unroll
            for (int reg = 0; reg < 4; ++reg) {
                float logit = acc[m][n][reg] + bd;
                if (v == yv[m][reg])
                    picked[rBase + m * 16 + (lane >> 4) * 4 + reg] = logit;
                rs[m][reg] += __expf(logit);
            }
    }
#pragma unroll
    for (int m = 0; m < 4; ++m)
#pragma unroll
        for (int reg = 0; reg < 4; ++reg) {
            float s = rs[m][reg];
            s += __shfl_xor(s, 1);
            s += __shfl_xor(s, 2);
            s += __shfl_xor(s, 4);
            s += __shfl_xor(s, 8);
            if ((lane & 15) == 0)
                atomicAdd(&sumexp[rBase + m * 16 + (lane >> 4) * 4 + reg], s);
        }
}

// ---------------------------------------------------------------------------
// K4: loss[b] = -sum_t (picked[b*T+t] - log(sumexp[b*T+t]))
// ---------------------------------------------------------------------------
__global__ void loss_kernel(const float* __restrict__ picked,
                            const float* __restrict__ sumexp,
                            float* __restrict__ out) {
    int b = threadIdx.x;
    if (b >= NB) return;
    float s = 0.f;
    for (int t = 0; t < NT; t++) {
        int r = b * NT + t;
        s += picked[r] - logf(sumexp[r]);
    }
    out[b] = -s;
}

// ---------------------------------------------------------------------------
extern "C" void kernel_launch(void* const* d_in, const int* in_sizes, int n_in,
                              void* d_out, int out_size, void* d_ws, size_t ws_size,
                              hipStream_t stream) {
    const int*   x     = (const int*)d_in[0];
    const int*   y     = (const int*)d_in[1];
    const float* ctx   = (const float*)d_in[2];
    const float* emb   = (const float*)d_in[3];
    const float* W_ih  = (const float*)d_in[4];
    const float* W_hh  = (const float*)d_in[5];
    const float* b_ih  = (const float*)d_in[6];
    const float* b_hh  = (const float*)d_in[7];
    const float* W_dec = (const float*)d_in[8];
    const float* b_dec = (const float*)d_in[9];
    float* out = (float*)d_out;

    // workspace carve
    float*          ws      = (float*)d_ws;
    float*          xg      = ws;                               // 8192*2048 f32  (64 MB)
    float*          sumexp  = xg + (size_t)BT * G4;             // 8192 f32
    float*          picked  = sumexp + BT;                      // 8192 f32
    unsigned short* inp_bf  = (unsigned short*)(picked + BT);   // 8192*384  bf16
    unsigned short* hs_bf   = inp_bf + (size_t)BT * ECK;        // 8192*512  bf16
    unsigned short* wdec_bf = hs_bf + (size_t)BT * NH;          // 16000*512 bf16
    unsigned short* whh_bf  = wdec_bf + (size_t)NV * NH;        // 2048*512  bf16
    unsigned short* wih_bf  = whh_bf + (size_t)G4 * NH;         // 2048*384  bf16
    unsigned short* h_bf    = wih_bf + (size_t)G4 * ECK;        // 2*128*512 bf16
    unsigned int*   bar     = (unsigned int*)(h_bf + 2 * NB * NH);  // 64*8 u32

    hipMemsetAsync(h_bf, 0, NB * NH * sizeof(unsigned short), stream);  // h0 = 0 (buf 0)
    hipMemsetAsync(bar, 0, NT * 8 * sizeof(unsigned int), stream);
    hipMemsetAsync(sumexp, 0, BT * sizeof(float), stream);

    f32_to_bf16<<<(NV * NH / 4 + 255) / 256, 256, 0, stream>>>(W_dec, wdec_bf, NV * NH / 4);
    f32_to_bf16<<<(G4 * NH / 4 + 255) / 256, 256, 0, stream>>>(W_hh, whh_bf, G4 * NH / 4);
    f32_to_bf16<<<(G4 * ECK / 4 + 255) / 256, 256, 0, stream>>>(W_ih, wih_bf, G4 * ECK / 4);

    build_inp_bf<<<(BT * (ECK / 4) + 255) / 256, 256, 0, stream>>>(x, ctx, emb, inp_bf);

    gemm_xg_bf<<<dim3(G4 / 128, BT / 128), 256, 0, stream>>>(inp_bf, wih_bf, b_ih, b_hh, xg);

    lstm_persistent<<<dim3(32, 8), 256, 0, stream>>>(whh_bf, xg, h_bf, hs_bf, bar);

    decoder_mfma<<<dim3(NV / 128, BT / 128), 256, 0, stream>>>(
        hs_bf, wdec_bf, b_dec, y, sumexp, picked);

    loss_kernel<<<1, 128, 0, stream>>>(picked, sumexp, out);
}

// Round 4
// 943.966 us; speedup vs baseline: 3.3246x; 1.5131x over previous
//
#include <hip/hip_runtime.h>
#include <cmath>

// Problem constants
#define NB   128      // batch
#define NT   64       // time
#define NV   16000    // vocab
#define NE   128      // emb dim
#define NC   256      // context dim
#define NH   512      // hidden
#define G4   2048     // 4*NH
#define ECK  384      // NE+NC
#define BT   8192     // NB*NT

typedef __attribute__((ext_vector_type(8))) short bf16x8;
typedef __attribute__((ext_vector_type(4))) float f32x4;
typedef const void __attribute__((address_space(1)))* gptr_t;
typedef void __attribute__((address_space(3)))* sptr_t;

static __device__ __forceinline__ unsigned short f2bf(float f) {
    union { float f; unsigned u; } a; a.f = f;
    unsigned r = (a.u + 0x7fff + ((a.u >> 16) & 1)) >> 16;   // RNE
    return (unsigned short)r;
}

// ---------------------------------------------------------------------------
// K0: build inp_bf[t*128+b][384] = bf16(concat(emb_table[x[b][t]], context[b]))
// ---------------------------------------------------------------------------
__global__ void build_inp_bf(const int* __restrict__ x, const float* __restrict__ ctx,
                             const float* __restrict__ emb, unsigned short* __restrict__ inp) {
    int f = blockIdx.x * blockDim.x + threadIdx.x;   // float4 index
    const int total = BT * (ECK / 4);
    if (f >= total) return;
    int row = f / (ECK / 4);
    int c4  = f % (ECK / 4);
    int b = row & (NB - 1);
    int c = c4 * 4;
    float4 v;
    if (c < NE) {
        int t = row >> 7;
        int tok = x[b * NT + t];
        v = *(const float4*)(emb + tok * NE + c);
    } else {
        v = *(const float4*)(ctx + b * NC + (c - NE));
    }
    ushort4 o;
    o.x = f2bf(v.x); o.y = f2bf(v.y); o.z = f2bf(v.z); o.w = f2bf(v.w);
    ((ushort4*)inp)[f] = o;
}

// ---------------------------------------------------------------------------
// K0b: fp32 -> bf16 convert (W_dec, W_hh, W_ih)
// ---------------------------------------------------------------------------
__global__ void f32_to_bf16(const float* __restrict__ src, unsigned short* __restrict__ dst, int n4) {
    int i = blockIdx.x * blockDim.x + threadIdx.x;
    if (i >= n4) return;
    float4 v = ((const float4*)src)[i];
    ushort4 o;
    o.x = f2bf(v.x); o.y = f2bf(v.y); o.z = f2bf(v.z); o.w = f2bf(v.w);
    ((ushort4*)dst)[i] = o;
}

// ---------------------------------------------------------------------------
// K1: xg = inp_bf @ W_ih^T + b_ih + b_hh  (bf16 MFMA, m97 structure, K=384)
// ---------------------------------------------------------------------------
__global__ __launch_bounds__(256, 2) void gemm_xg_bf(
    const unsigned short* __restrict__ A,   // inp_bf [BT][384]
    const unsigned short* __restrict__ Bw,  // wih_bf [2048][384]
    const float* __restrict__ b_ih, const float* __restrict__ b_hh,
    float* __restrict__ xg)                 // [BT][2048] f32
{
    __shared__ short As[128 * 64];
    __shared__ short Bs[128 * 64];
    const int tid  = threadIdx.x;
    const int lane = tid & 63;
    const int wv   = tid >> 6;
    const int wr   = wv >> 1, wc = wv & 1;
    const int rowBase = blockIdx.y * 128;
    const int colBase = blockIdx.x * 128;

    f32x4 acc[4][4];
#pragma unroll
    for (int m = 0; m < 4; m++)
#pragma unroll
        for (int n = 0; n < 4; n++) acc[m][n] = (f32x4){0.f, 0.f, 0.f, 0.f};

    for (int kb = 0; kb < ECK; kb += 64) {
#pragma unroll
        for (int i = 0; i < 4; ++i) {
            int f = tid + i * 256;
            int r = f >> 3, pc = f & 7;
            int lc = pc ^ (r & 7);
            const unsigned short* srcA = A  + (size_t)(rowBase + r) * ECK + kb + lc * 8;
            const unsigned short* srcB = Bw + (size_t)(colBase + r) * ECK + kb + lc * 8;
            __builtin_amdgcn_global_load_lds((gptr_t)srcA, (sptr_t)(As + f * 8), 16, 0, 0);
            __builtin_amdgcn_global_load_lds((gptr_t)srcB, (sptr_t)(Bs + f * 8), 16, 0, 0);
        }
        __syncthreads();
#pragma unroll
        for (int kk = 0; kk < 2; ++kk) {
            bf16x8 af[4], bfr[4];
#pragma unroll
            for (int m = 0; m < 4; ++m) {
                int r  = wr * 64 + m * 16 + (lane & 15);
                int pc = (kk * 4 + (lane >> 4)) ^ (r & 7);
                af[m] = *(const bf16x8*)(As + r * 64 + pc * 8);
            }
#pragma unroll
            for (int n = 0; n < 4; ++n) {
                int r  = wc * 64 + n * 16 + (lane & 15);
                int pc = (kk * 4 + (lane >> 4)) ^ (r & 7);
                bfr[n] = *(const bf16x8*)(Bs + r * 64 + pc * 8);
            }
#pragma unroll
            for (int m = 0; m < 4; ++m)
#pragma unroll
                for (int n = 0; n < 4; ++n)
                    acc[m][n] = __builtin_amdgcn_mfma_f32_16x16x32_bf16(af[m], bfr[n], acc[m][n], 0, 0, 0);
        }
        __syncthreads();
    }
    const int rBase = rowBase + wr * 64;
    const int cBase = colBase + wc * 64;
#pragma unroll
    for (int n = 0; n < 4; ++n) {
        int col = cBase + n * 16 + (lane & 15);
        float bias = b_ih[col] + b_hh[col];
#pragma unroll
        for (int m = 0; m < 4; ++m)
#pragma unroll
            for (int reg = 0; reg < 4; ++reg) {
                int row = rBase + m * 16 + (lane >> 4) * 4 + reg;
                xg[(size_t)row * G4 + col] = acc[m][n][reg] + bias;
            }
    }
}

// ---------------------------------------------------------------------------
// K2: persistent LSTM — all 64 timesteps in one kernel.
// Grid (32 hb, 8 bb) = 256 blocks (1/CU), 256 threads.
// Cross-block h exchange via fine-grained agent-scope atomics (IC coherence,
// NO bulk wbl2/inv fences). xg prefetched into regs before the barrier spin.
// ---------------------------------------------------------------------------
__global__ __launch_bounds__(256, 1) void lstm_persistent(
    const unsigned short* __restrict__ whh_bf,      // [2048][512] bf16
    const float* __restrict__ xg,                   // [BT][2048] f32, row t*128+b
    unsigned long long* __restrict__ h_ex,          // [2][128][128] u64=bf16x4 (buf0 zeroed)
    unsigned short* __restrict__ hs_bf,             // [8192][512] bf16, row b*64+t
    unsigned int* __restrict__ bar)                 // [64][8] zeroed
{
    __shared__ short Ws[64 * 512];     // 64 KB W_hh slice (rows c=g*16+j)
    __shared__ short As[16 * 512];     // 16 KB staged h panel (chunk-swizzled)
    __shared__ float Cs[16][64];       // C scratch
    __shared__ float cst[256];         // persistent c state
    __shared__ unsigned short hpk[256]; // h patch pack buffer [b*16+j]
    const int tid  = threadIdx.x;
    const int lane = tid & 63;
    const int wv   = tid >> 6;
    const int hb = blockIdx.x, bb = blockIdx.y;
    const int hBase = hb * 16;
    const int bBase = bb * 16;

    // stage W slice once; LDS slot ch of row r holds logical chunk ch^(r&7)
#pragma unroll
    for (int i = 0; i < 16; ++i) {
        int f = tid + i * 256;
        int r = f >> 6, ch = f & 63;
        int g = r >> 4, j = r & 15;
        const unsigned short* src = whh_bf + (size_t)((g << 9) + hBase + j) * NH + ((ch ^ (r & 7)) << 3);
        __builtin_amdgcn_global_load_lds((gptr_t)src, (sptr_t)(Ws + f * 8), 16, 0, 0);
    }
    cst[tid] = 0.f;
    __syncthreads();

    const int gb = tid >> 4, gj = tid & 15;          // gate-stage mapping
    const int hAbs = hBase + gj;

#pragma unroll 1
    for (int t = 0; t < NT; ++t) {
        // --- prefetch xg for this step (barrier-independent; hides HBM latency)
        const float* xgr = xg + (size_t)(t * NB + bBase + gb) * G4 + hAbs;
        float x0 = xgr[0];
        float x1 = xgr[NH];
        float x2 = xgr[2 * NH];
        float x3 = xgr[3 * NH];

        // --- wait for step t's h panel (produced at step t-1)
        if (t > 0) {
            if (tid == 0) {
                while (__hip_atomic_load(&bar[(t - 1) * 8 + bb], __ATOMIC_RELAXED,
                                         __HIP_MEMORY_SCOPE_AGENT) < 32u)
                    __builtin_amdgcn_s_sleep(1);
            }
            __syncthreads();
        }

        // --- stage h[bBase..+15][0..511]: agent atomic u64 loads (bypass stale
        //     L1/L2, read IC) + swizzled ds_write_b64
        const unsigned long long* hsrc = h_ex + (size_t)(t & 1) * NB * (NH / 4);
#pragma unroll
        for (int i = 0; i < 8; ++i) {
            int f = tid + i * 256;            // u64 index, 0..2047
            int r = f >> 7;                   // row 0..15
            int hc = f & 127;                 // half-chunk (4 ushorts)
            unsigned long long v = __hip_atomic_load(
                &hsrc[(size_t)(bBase + r) * (NH / 4) + hc],
                __ATOMIC_RELAXED, __HIP_MEMORY_SCOPE_AGENT);
            int sw = (hc >> 1) ^ (r & 7);
            *(unsigned long long*)(As + r * 512 + sw * 8 + (hc & 1) * 4) = v;
        }
        __syncthreads();

        // --- C[16][64] = h(16x512) @ Ws(64x512)^T ; wave wv owns n-tile wv
        f32x4 acc = (f32x4){0.f, 0.f, 0.f, 0.f};
        const int ar = lane & 15;
        const int br = wv * 16 + (lane & 15);
#pragma unroll
        for (int kc = 0; kc < 16; ++kc) {
            int cA = (kc * 4 + (lane >> 4)) ^ (ar & 7);
            int cB = (kc * 4 + (lane >> 4)) ^ (br & 7);
            bf16x8 a = *(const bf16x8*)(As + ar * 512 + cA * 8);
            bf16x8 b = *(const bf16x8*)(Ws + br * 512 + cB * 8);
            acc = __builtin_amdgcn_mfma_f32_16x16x32_bf16(a, b, acc, 0, 0, 0);
        }
#pragma unroll
        for (int reg = 0; reg < 4; ++reg)
            Cs[(lane >> 4) * 4 + reg][wv * 16 + (lane & 15)] = acc[reg];
        __syncthreads();

        // --- gates (thread -> b=gb, j=gj) using prefetched xg
        {
            float gi = Cs[gb][gj]      + x0;
            float gf = Cs[gb][16 + gj] + x1;
            float gg = Cs[gb][32 + gj] + x2;
            float go = Cs[gb][48 + gj] + x3;
            float i_ = 1.f / (1.f + __expf(-gi));
            float f_ = 1.f / (1.f + __expf(-gf));
            float o_ = 1.f / (1.f + __expf(-go));
            float cp = cst[tid];
            float cn = f_ * cp + i_ * tanhf(gg);
            float hn = o_ * tanhf(cn);
            cst[tid] = cn;
            unsigned short h16 = f2bf(hn);
            hs_bf[((size_t)(bBase + gb) * NT + t) * NH + hAbs] = h16;  // normal store
            hpk[tid] = h16;
        }
        __syncthreads();

        // --- publish h patch: wave 0 does 64 agent atomic u64 stores (to IC)
        if (t < NT - 1) {
            if (tid < 64) {
                int b = tid >> 2, q = tid & 3;
                unsigned long long v = *(const unsigned long long*)&hpk[b * 16 + q * 4];
                __hip_atomic_store(
                    &h_ex[(size_t)((t + 1) & 1) * NB * (NH / 4)
                          + (size_t)(bBase + b) * (NH / 4) + (hBase >> 2) + q],
                    v, __ATOMIC_RELAXED, __HIP_MEMORY_SCOPE_AGENT);
            }
            // hand-rolled release: wave0 waits its stores complete at IC, then flag
            asm volatile("s_waitcnt vmcnt(0)" ::: "memory");
            if (tid == 0)
                __hip_atomic_fetch_add(&bar[t * 8 + bb], 1u, __ATOMIC_RELAXED,
                                       __HIP_MEMORY_SCOPE_AGENT);
            __syncthreads();   // keep hpk stable until stores done
        }
    }
}

// ---------------------------------------------------------------------------
// K3: decoder GEMM (bf16 MFMA) + fused log-sum-exp.
// ---------------------------------------------------------------------------
__global__ __launch_bounds__(256, 2) void decoder_mfma(
    const unsigned short* __restrict__ A,   // hs_bf [BT][512]
    const unsigned short* __restrict__ Bw,  // W_dec_bf [16000][512]
    const float* __restrict__ b_dec,
    const int* __restrict__ y,
    float* __restrict__ sumexp,
    float* __restrict__ picked)
{
    __shared__ short As[128 * 64];
    __shared__ short Bs[128 * 64];
    const int tid  = threadIdx.x;
    const int lane = tid & 63;
    const int wv   = tid >> 6;
    const int wr   = wv >> 1, wc = wv & 1;
    const int rowBase = blockIdx.y * 128;
    const int colBase = blockIdx.x * 128;

    f32x4 acc[4][4];
#pragma unroll
    for (int m = 0; m < 4; m++)
#pragma unroll
        for (int n = 0; n < 4; n++) acc[m][n] = (f32x4){0.f, 0.f, 0.f, 0.f};

    for (int kb = 0; kb < NH; kb += 64) {
#pragma unroll
        for (int i = 0; i < 4; ++i) {
            int f = tid + i * 256;
            int r = f >> 3, pc = f & 7;
            int lc = pc ^ (r & 7);
            const unsigned short* srcA = A  + (size_t)(rowBase + r) * NH + kb + lc * 8;
            const unsigned short* srcB = Bw + (size_t)(colBase + r) * NH + kb + lc * 8;
            __builtin_amdgcn_global_load_lds((gptr_t)srcA, (sptr_t)(As + f * 8), 16, 0, 0);
            __builtin_amdgcn_global_load_lds((gptr_t)srcB, (sptr_t)(Bs + f * 8), 16, 0, 0);
        }
        __syncthreads();
#pragma unroll
        for (int kk = 0; kk < 2; ++kk) {
            bf16x8 af[4], bfr[4];
#pragma unroll
            for (int m = 0; m < 4; ++m) {
                int r  = wr * 64 + m * 16 + (lane & 15);
                int pc = (kk * 4 + (lane >> 4)) ^ (r & 7);
                af[m] = *(const bf16x8*)(As + r * 64 + pc * 8);
            }
#pragma unroll
            for (int n = 0; n < 4; ++n) {
                int r  = wc * 64 + n * 16 + (lane & 15);
                int pc = (kk * 4 + (lane >> 4)) ^ (r & 7);
                bfr[n] = *(const bf16x8*)(Bs + r * 64 + pc * 8);
            }
#pragma unroll
            for (int m = 0; m < 4; ++m)
#pragma unroll
                for (int n = 0; n < 4; ++n)
                    acc[m][n] = __builtin_amdgcn_mfma_f32_16x16x32_bf16(af[m], bfr[n], acc[m][n], 0, 0, 0);
        }
        __syncthreads();
    }

    const int rBase = rowBase + wr * 64;
    const int cBase = colBase + wc * 64;
    int yv[4][4];
#pragma unroll
    for (int m = 0; m < 4; ++m)
#pragma unroll
        for (int reg = 0; reg < 4; ++reg)
            yv[m][reg] = y[rBase + m * 16 + (lane >> 4) * 4 + reg];

    float rs[4][4];
#pragma unroll
    for (int m = 0; m < 4; ++m)
#pragma unroll
        for (int reg = 0; reg < 4; ++reg) rs[m][reg] = 0.f;

#pragma unroll
    for (int n = 0; n < 4; ++n) {
        int v = cBase + n * 16 + (lane & 15);
        float bd = b_dec[v];
#pragma unroll
        for (int m = 0; m < 4; ++m)
#pragma unroll
            for (int reg = 0; reg < 4; ++reg) {
                float logit = acc[m][n][reg] + bd;
                if (v == yv[m][reg])
                    picked[rBase + m * 16 + (lane >> 4) * 4 + reg] = logit;
                rs[m][reg] += __expf(logit);
            }
    }
#pragma unroll
    for (int m = 0; m < 4; ++m)
#pragma unroll
        for (int reg = 0; reg < 4; ++reg) {
            float s = rs[m][reg];
            s += __shfl_xor(s, 1);
            s += __shfl_xor(s, 2);
            s += __shfl_xor(s, 4);
            s += __shfl_xor(s, 8);
            if ((lane & 15) == 0)
                atomicAdd(&sumexp[rBase + m * 16 + (lane >> 4) * 4 + reg], s);
        }
}

// ---------------------------------------------------------------------------
// K4: loss[b] = -sum_t (picked[b*T+t] - log(sumexp[b*T+t]))
// ---------------------------------------------------------------------------
__global__ void loss_kernel(const float* __restrict__ picked,
                            const float* __restrict__ sumexp,
                            float* __restrict__ out) {
    int b = threadIdx.x;
    if (b >= NB) return;
    float s = 0.f;
    for (int t = 0; t < NT; t++) {
        int r = b * NT + t;
        s += picked[r] - logf(sumexp[r]);
    }
    out[b] = -s;
}

// ---------------------------------------------------------------------------
extern "C" void kernel_launch(void* const* d_in, const int* in_sizes, int n_in,
                              void* d_out, int out_size, void* d_ws, size_t ws_size,
                              hipStream_t stream) {
    const int*   x     = (const int*)d_in[0];
    const int*   y     = (const int*)d_in[1];
    const float* ctx   = (const float*)d_in[2];
    const float* emb   = (const float*)d_in[3];
    const float* W_ih  = (const float*)d_in[4];
    const float* W_hh  = (const float*)d_in[5];
    const float* b_ih  = (const float*)d_in[6];
    const float* b_hh  = (const float*)d_in[7];
    const float* W_dec = (const float*)d_in[8];
    const float* b_dec = (const float*)d_in[9];
    float* out = (float*)d_out;

    // workspace carve
    float*          ws      = (float*)d_ws;
    float*          xg      = ws;                               // 8192*2048 f32 (64 MB)
    float*          sumexp  = xg + (size_t)BT * G4;             // 8192 f32
    float*          picked  = sumexp + BT;                      // 8192 f32
    unsigned short* inp_bf  = (unsigned short*)(picked + BT);   // 8192*384  bf16
    unsigned short* hs_bf   = inp_bf + (size_t)BT * ECK;        // 8192*512  bf16
    unsigned short* wdec_bf = hs_bf + (size_t)BT * NH;          // 16000*512 bf16
    unsigned short* whh_bf  = wdec_bf + (size_t)NV * NH;        // 2048*512  bf16
    unsigned short* wih_bf  = whh_bf + (size_t)G4 * NH;         // 2048*384  bf16
    unsigned long long* h_ex = (unsigned long long*)(wih_bf + (size_t)G4 * ECK); // [2][128][128] u64
    unsigned int*   bar     = (unsigned int*)(h_ex + 2 * NB * (NH / 4));         // 64*8 u32

    hipMemsetAsync(h_ex, 0, NB * (NH / 4) * sizeof(unsigned long long), stream); // h0 = 0 (buf 0)
    hipMemsetAsync(bar, 0, NT * 8 * sizeof(unsigned int), stream);
    hipMemsetAsync(sumexp, 0, BT * sizeof(float), stream);

    f32_to_bf16<<<(NV * NH / 4 + 255) / 256, 256, 0, stream>>>(W_dec, wdec_bf, NV * NH / 4);
    f32_to_bf16<<<(G4 * NH / 4 + 255) / 256, 256, 0, stream>>>(W_hh, whh_bf, G4 * NH / 4);
    f32_to_bf16<<<(G4 * ECK / 4 + 255) / 256, 256, 0, stream>>>(W_ih, wih_bf, G4 * ECK / 4);

    build_inp_bf<<<(BT * (ECK / 4) + 255) / 256, 256, 0, stream>>>(x, ctx, emb, inp_bf);

    gemm_xg_bf<<<dim3(G4 / 128, BT / 128), 256, 0, stream>>>(inp_bf, wih_bf, b_ih, b_hh, xg);

    lstm_persistent<<<dim3(32, 8), 256, 0, stream>>>(whh_bf, xg, h_ex, hs_bf, bar);

    decoder_mfma<<<dim3(NV / 128, BT / 128), 256, 0, stream>>>(
        hs_bf, wdec_bf, b_dec, y, sumexp, picked);

    loss_kernel<<<1, 128, 0, stream>>>(picked, sumexp, out);
}

// Round 5
// 602.358 us; speedup vs baseline: 5.2101x; 1.5671x over previous
//
#include <hip/hip_runtime.h>
#include <cmath>

// Problem constants
#define NB   128      // batch
#define NT   64       // time
#define NV   16000    // vocab
#define NE   128      // emb dim
#define NC   256      // context dim
#define NH   512      // hidden
#define G4   2048     // 4*NH
#define ECK  384      // NE+NC
#define BT   8192     // NB*NT

typedef __attribute__((ext_vector_type(8))) short bf16x8;
typedef __attribute__((ext_vector_type(4))) float f32x4;
typedef const void __attribute__((address_space(1)))* gptr_t;
typedef void __attribute__((address_space(3)))* sptr_t;

static __device__ __forceinline__ unsigned short f2bf(float f) {
    union { float f; unsigned u; } a; a.f = f;
    unsigned r = (a.u + 0x7fff + ((a.u >> 16) & 1)) >> 16;   // RNE
    return (unsigned short)r;
}

// ---------------------------------------------------------------------------
// K0: build inp_bf[t*128+b][384] = bf16(concat(emb_table[x[b][t]], context[b]))
// ---------------------------------------------------------------------------
__global__ void build_inp_bf(const int* __restrict__ x, const float* __restrict__ ctx,
                             const float* __restrict__ emb, unsigned short* __restrict__ inp) {
    int f = blockIdx.x * blockDim.x + threadIdx.x;   // float4 index
    const int total = BT * (ECK / 4);
    if (f >= total) return;
    int row = f / (ECK / 4);
    int c4  = f % (ECK / 4);
    int b = row & (NB - 1);
    int c = c4 * 4;
    float4 v;
    if (c < NE) {
        int t = row >> 7;
        int tok = x[b * NT + t];
        v = *(const float4*)(emb + tok * NE + c);
    } else {
        v = *(const float4*)(ctx + b * NC + (c - NE));
    }
    ushort4 o;
    o.x = f2bf(v.x); o.y = f2bf(v.y); o.z = f2bf(v.z); o.w = f2bf(v.w);
    ((ushort4*)inp)[f] = o;
}

// ---------------------------------------------------------------------------
// K0b: fp32 -> bf16 convert (W_dec, W_hh, W_ih)
// ---------------------------------------------------------------------------
__global__ void f32_to_bf16(const float* __restrict__ src, unsigned short* __restrict__ dst, int n4) {
    int i = blockIdx.x * blockDim.x + threadIdx.x;
    if (i >= n4) return;
    float4 v = ((const float4*)src)[i];
    ushort4 o;
    o.x = f2bf(v.x); o.y = f2bf(v.y); o.z = f2bf(v.z); o.w = f2bf(v.w);
    ((ushort4*)dst)[i] = o;
}

// ---------------------------------------------------------------------------
// K1: xg = inp_bf @ W_ih^T + b_ih + b_hh  (bf16 MFMA, m97 structure, K=384)
// ---------------------------------------------------------------------------
__global__ __launch_bounds__(256, 2) void gemm_xg_bf(
    const unsigned short* __restrict__ A,   // inp_bf [BT][384]
    const unsigned short* __restrict__ Bw,  // wih_bf [2048][384]
    const float* __restrict__ b_ih, const float* __restrict__ b_hh,
    float* __restrict__ xg)                 // [BT][2048] f32
{
    __shared__ short As[128 * 64];
    __shared__ short Bs[128 * 64];
    const int tid  = threadIdx.x;
    const int lane = tid & 63;
    const int wv   = tid >> 6;
    const int wr   = wv >> 1, wc = wv & 1;
    const int rowBase = blockIdx.y * 128;
    const int colBase = blockIdx.x * 128;

    f32x4 acc[4][4];
#pragma unroll
    for (int m = 0; m < 4; m++)
#pragma unroll
        for (int n = 0; n < 4; n++) acc[m][n] = (f32x4){0.f, 0.f, 0.f, 0.f};

    for (int kb = 0; kb < ECK; kb += 64) {
#pragma unroll
        for (int i = 0; i < 4; ++i) {
            int f = tid + i * 256;
            int r = f >> 3, pc = f & 7;
            int lc = pc ^ (r & 7);
            const unsigned short* srcA = A  + (size_t)(rowBase + r) * ECK + kb + lc * 8;
            const unsigned short* srcB = Bw + (size_t)(colBase + r) * ECK + kb + lc * 8;
            __builtin_amdgcn_global_load_lds((gptr_t)srcA, (sptr_t)(As + f * 8), 16, 0, 0);
            __builtin_amdgcn_global_load_lds((gptr_t)srcB, (sptr_t)(Bs + f * 8), 16, 0, 0);
        }
        __syncthreads();
#pragma unroll
        for (int kk = 0; kk < 2; ++kk) {
            bf16x8 af[4], bfr[4];
#pragma unroll
            for (int m = 0; m < 4; ++m) {
                int r  = wr * 64 + m * 16 + (lane & 15);
                int pc = (kk * 4 + (lane >> 4)) ^ (r & 7);
                af[m] = *(const bf16x8*)(As + r * 64 + pc * 8);
            }
#pragma unroll
            for (int n = 0; n < 4; ++n) {
                int r  = wc * 64 + n * 16 + (lane & 15);
                int pc = (kk * 4 + (lane >> 4)) ^ (r & 7);
                bfr[n] = *(const bf16x8*)(Bs + r * 64 + pc * 8);
            }
#pragma unroll
            for (int m = 0; m < 4; ++m)
#pragma unroll
                for (int n = 0; n < 4; ++n)
                    acc[m][n] = __builtin_amdgcn_mfma_f32_16x16x32_bf16(af[m], bfr[n], acc[m][n], 0, 0, 0);
        }
        __syncthreads();
    }
    const int rBase = rowBase + wr * 64;
    const int cBase = colBase + wc * 64;
#pragma unroll
    for (int n = 0; n < 4; ++n) {
        int col = cBase + n * 16 + (lane & 15);
        float bias = b_ih[col] + b_hh[col];
#pragma unroll
        for (int m = 0; m < 4; ++m)
#pragma unroll
            for (int reg = 0; reg < 4; ++reg) {
                int row = rBase + m * 16 + (lane >> 4) * 4 + reg;
                xg[(size_t)row * G4 + col] = acc[m][n][reg] + bias;
            }
    }
}

// ---------------------------------------------------------------------------
// K2: persistent LSTM — all 64 timesteps in one kernel.
// 1-D grid 256 blocks: bb = bid&7 (batch group, XCD co-location heuristic),
// hb = bid>>3 (h-slice). Producer publishes h via agent-atomic u64 stores
// (write-through to IC), sets a PER-PRODUCER flag (plain store, no RMW).
// Consumers poll 32 flags in parallel, then stage the h panel via NORMAL
// cached global_load_lds (per-step buffers -> no stale lines; XCD L2 amortizes).
// ---------------------------------------------------------------------------
__global__ __launch_bounds__(256, 1) void lstm_persistent(
    const unsigned short* __restrict__ whh_bf,      // [2048][512] bf16
    const float* __restrict__ xg,                   // [BT][2048] f32, row t*128+b
    unsigned short* __restrict__ hx,                // [NT][128][512] bf16 (hx[0] zeroed)
    unsigned short* __restrict__ hs_bf,             // [8192][512] bf16, row b*64+t
    unsigned int* __restrict__ flags)               // [NT][8][32] zeroed
{
    __shared__ short Ws[64 * 512];      // 64 KB W_hh slice (rows c=g*16+j)
    __shared__ short As[16 * 512];      // 16 KB staged h panel (chunk-swizzled)
    __shared__ float Cs[16][68];        // C scratch (padded: 2-way max)
    __shared__ float cst[256];          // persistent c state
    __shared__ unsigned short hpk[256]; // h patch pack buffer [b*16+j]
    const int tid  = threadIdx.x;
    const int lane = tid & 63;
    const int wv   = tid >> 6;
    const int bid  = blockIdx.x;
    const int bb = bid & 7;             // batch group -> same XCD (heuristic)
    const int hb = bid >> 3;            // h-slice
    const int hBase = hb * 16;
    const int bBase = bb * 16;

    unsigned long long* hx64 = (unsigned long long*)hx;

    // stage W slice once; LDS slot ch of row r holds logical chunk ch^(r&7)
#pragma unroll
    for (int i = 0; i < 16; ++i) {
        int f = tid + i * 256;
        int r = f >> 6, ch = f & 63;
        int g = r >> 4, j = r & 15;
        const unsigned short* src = whh_bf + (size_t)((g << 9) + hBase + j) * NH + ((ch ^ (r & 7)) << 3);
        __builtin_amdgcn_global_load_lds((gptr_t)src, (sptr_t)(Ws + f * 8), 16, 0, 0);
    }
    cst[tid] = 0.f;
    __syncthreads();

    const int gb = tid >> 4, gj = tid & 15;          // gate-stage mapping
    const int hAbs = hBase + gj;

#pragma unroll 1
    for (int t = 0; t < NT; ++t) {
        // --- prefetch xg for this step (barrier-independent; hides HBM latency)
        const float* xgr = xg + (size_t)(t * NB + bBase + gb) * G4 + hAbs;
        float x0 = xgr[0];
        float x1 = xgr[NH];
        float x2 = xgr[2 * NH];
        float x3 = xgr[3 * NH];

        // --- wait for step t's h panel (written at end of step t-1)
        if (t > 0) {
            const unsigned int* fl = flags + (size_t)(t - 1) * 256 + bb * 32;
            unsigned int v;
            do {
                v = __hip_atomic_load(&fl[lane & 31], __ATOMIC_RELAXED,
                                      __HIP_MEMORY_SCOPE_AGENT);
            } while (!__all(v != 0));
        }

        // --- stage h panel: NORMAL cached global_load_lds (w=16), swizzled source
        const unsigned short* hsrc = hx + (size_t)t * NB * NH;
#pragma unroll
        for (int i = 0; i < 4; ++i) {
            int f = tid + i * 256;
            int r = f >> 6, ch = f & 63;
            const unsigned short* src = hsrc + (size_t)(bBase + r) * NH + ((ch ^ (r & 7)) << 3);
            __builtin_amdgcn_global_load_lds((gptr_t)src, (sptr_t)(As + f * 8), 16, 0, 0);
        }
        __syncthreads();

        // --- C[16][64] = h(16x512) @ Ws(64x512)^T ; wave wv owns n-tile wv
        f32x4 acc = (f32x4){0.f, 0.f, 0.f, 0.f};
        const int ar = lane & 15;
        const int br = wv * 16 + (lane & 15);
#pragma unroll
        for (int kc = 0; kc < 16; ++kc) {
            int cA = (kc * 4 + (lane >> 4)) ^ (ar & 7);
            int cB = (kc * 4 + (lane >> 4)) ^ (br & 7);
            bf16x8 a = *(const bf16x8*)(As + ar * 512 + cA * 8);
            bf16x8 b = *(const bf16x8*)(Ws + br * 512 + cB * 8);
            acc = __builtin_amdgcn_mfma_f32_16x16x32_bf16(a, b, acc, 0, 0, 0);
        }
#pragma unroll
        for (int reg = 0; reg < 4; ++reg)
            Cs[(lane >> 4) * 4 + reg][wv * 16 + (lane & 15)] = acc[reg];
        __syncthreads();

        // --- gates (thread -> b=gb, j=gj) using prefetched xg
        {
            float gi = Cs[gb][gj]      + x0;
            float gf = Cs[gb][16 + gj] + x1;
            float gg = Cs[gb][32 + gj] + x2;
            float go = Cs[gb][48 + gj] + x3;
            float i_ = 1.f / (1.f + __expf(-gi));
            float f_ = 1.f / (1.f + __expf(-gf));
            float o_ = 1.f / (1.f + __expf(-go));
            float cp = cst[tid];
            float cn = f_ * cp + i_ * tanhf(gg);
            float hn = o_ * tanhf(cn);
            cst[tid] = cn;
            unsigned short h16 = f2bf(hn);
            hs_bf[((size_t)(bBase + gb) * NT + t) * NH + hAbs] = h16;  // normal store
            hpk[tid] = h16;
        }
        __syncthreads();

        // --- publish h patch -> hx[t+1] (agent atomics, write-through to IC),
        //     then per-producer flag (plain agent store, NO RMW)
        if (t < NT - 1) {
            if (wv == 0) {
                int b = lane >> 2, q = lane & 3;
                unsigned long long v = *(const unsigned long long*)&hpk[b * 16 + q * 4];
                __hip_atomic_store(
                    &hx64[(size_t)(t + 1) * NB * (NH / 4)
                          + (size_t)(bBase + b) * (NH / 4) + (hBase >> 2) + q],
                    v, __ATOMIC_RELAXED, __HIP_MEMORY_SCOPE_AGENT);
                asm volatile("s_waitcnt vmcnt(0)" ::: "memory");   // complete at IC
                if (lane == 0)
                    __hip_atomic_store(&flags[(size_t)t * 256 + bb * 32 + hb], 1u,
                                       __ATOMIC_RELAXED, __HIP_MEMORY_SCOPE_AGENT);
            }
            __syncthreads();   // hpk stable until wave0 consumed it
        }
    }
}

// ---------------------------------------------------------------------------
// K3: decoder GEMM (bf16 MFMA) + fused log-sum-exp.
// ---------------------------------------------------------------------------
__global__ __launch_bounds__(256, 2) void decoder_mfma(
    const unsigned short* __restrict__ A,   // hs_bf [BT][512]
    const unsigned short* __restrict__ Bw,  // W_dec_bf [16000][512]
    const float* __restrict__ b_dec,
    const int* __restrict__ y,
    float* __restrict__ sumexp,
    float* __restrict__ picked)
{
    __shared__ short As[128 * 64];
    __shared__ short Bs[128 * 64];
    const int tid  = threadIdx.x;
    const int lane = tid & 63;
    const int wv   = tid >> 6;
    const int wr   = wv >> 1, wc = wv & 1;
    const int rowBase = blockIdx.y * 128;
    const int colBase = blockIdx.x * 128;

    f32x4 acc[4][4];
#pragma unroll
    for (int m = 0; m < 4; m++)
#pragma unroll
        for (int n = 0; n < 4; n++) acc[m][n] = (f32x4){0.f, 0.f, 0.f, 0.f};

    for (int kb = 0; kb < NH; kb += 64) {
#pragma unroll
        for (int i = 0; i < 4; ++i) {
            int f = tid + i * 256;
            int r = f >> 3, pc = f & 7;
            int lc = pc ^ (r & 7);
            const unsigned short* srcA = A  + (size_t)(rowBase + r) * NH + kb + lc * 8;
            const unsigned short* srcB = Bw + (size_t)(colBase + r) * NH + kb + lc * 8;
            __builtin_amdgcn_global_load_lds((gptr_t)srcA, (sptr_t)(As + f * 8), 16, 0, 0);
            __builtin_amdgcn_global_load_lds((gptr_t)srcB, (sptr_t)(Bs + f * 8), 16, 0, 0);
        }
        __syncthreads();
#pragma unroll
        for (int kk = 0; kk < 2; ++kk) {
            bf16x8 af[4], bfr[4];
#pragma unroll
            for (int m = 0; m < 4; ++m) {
                int r  = wr * 64 + m * 16 + (lane & 15);
                int pc = (kk * 4 + (lane >> 4)) ^ (r & 7);
                af[m] = *(const bf16x8*)(As + r * 64 + pc * 8);
            }
#pragma unroll
            for (int n = 0; n < 4; ++n) {
                int r  = wc * 64 + n * 16 + (lane & 15);
                int pc = (kk * 4 + (lane >> 4)) ^ (r & 7);
                bfr[n] = *(const bf16x8*)(Bs + r * 64 + pc * 8);
            }
#pragma unroll
            for (int m = 0; m < 4; ++m)
#pragma unroll
                for (int n = 0; n < 4; ++n)
                    acc[m][n] = __builtin_amdgcn_mfma_f32_16x16x32_bf16(af[m], bfr[n], acc[m][n], 0, 0, 0);
        }
        __syncthreads();
    }

    const int rBase = rowBase + wr * 64;
    const int cBase = colBase + wc * 64;
    int yv[4][4];
#pragma unroll
    for (int m = 0; m < 4; ++m)
#pragma unroll
        for (int reg = 0; reg < 4; ++reg)
            yv[m][reg] = y[rBase + m * 16 + (lane >> 4) * 4 + reg];

    float rs[4][4];
#pragma unroll
    for (int m = 0; m < 4; ++m)
#pragma unroll
        for (int reg = 0; reg < 4; ++reg) rs[m][reg] = 0.f;

#pragma unroll
    for (int n = 0; n < 4; ++n) {
        int v = cBase + n * 16 + (lane & 15);
        float bd = b_dec[v];
#pragma unroll
        for (int m = 0; m < 4; ++m)
#pragma unroll
            for (int reg = 0; reg < 4; ++reg) {
                float logit = acc[m][n][reg] + bd;
                if (v == yv[m][reg])
                    picked[rBase + m * 16 + (lane >> 4) * 4 + reg] = logit;
                rs[m][reg] += __expf(logit);
            }
    }
#pragma unroll
    for (int m = 0; m < 4; ++m)
#pragma unroll
        for (int reg = 0; reg < 4; ++reg) {
            float s = rs[m][reg];
            s += __shfl_xor(s, 1);
            s += __shfl_xor(s, 2);
            s += __shfl_xor(s, 4);
            s += __shfl_xor(s, 8);
            if ((lane & 15) == 0)
                atomicAdd(&sumexp[rBase + m * 16 + (lane >> 4) * 4 + reg], s);
        }
}

// ---------------------------------------------------------------------------
// K4: loss[b] = -sum_t (picked[b*T+t] - log(sumexp[b*T+t]))
// ---------------------------------------------------------------------------
__global__ void loss_kernel(const float* __restrict__ picked,
                            const float* __restrict__ sumexp,
                            float* __restrict__ out) {
    int b = threadIdx.x;
    if (b >= NB) return;
    float s = 0.f;
    for (int t = 0; t < NT; t++) {
        int r = b * NT + t;
        s += picked[r] - logf(sumexp[r]);
    }
    out[b] = -s;
}

// ---------------------------------------------------------------------------
extern "C" void kernel_launch(void* const* d_in, const int* in_sizes, int n_in,
                              void* d_out, int out_size, void* d_ws, size_t ws_size,
                              hipStream_t stream) {
    const int*   x     = (const int*)d_in[0];
    const int*   y     = (const int*)d_in[1];
    const float* ctx   = (const float*)d_in[2];
    const float* emb   = (const float*)d_in[3];
    const float* W_ih  = (const float*)d_in[4];
    const float* W_hh  = (const float*)d_in[5];
    const float* b_ih  = (const float*)d_in[6];
    const float* b_hh  = (const float*)d_in[7];
    const float* W_dec = (const float*)d_in[8];
    const float* b_dec = (const float*)d_in[9];
    float* out = (float*)d_out;

    // workspace carve
    float*          ws      = (float*)d_ws;
    float*          xg      = ws;                               // 8192*2048 f32 (64 MB)
    float*          sumexp  = xg + (size_t)BT * G4;             // 8192 f32
    float*          picked  = sumexp + BT;                      // 8192 f32
    unsigned short* inp_bf  = (unsigned short*)(picked + BT);   // 8192*384  bf16
    unsigned short* hs_bf   = inp_bf + (size_t)BT * ECK;        // 8192*512  bf16
    unsigned short* wdec_bf = hs_bf + (size_t)BT * NH;          // 16000*512 bf16
    unsigned short* whh_bf  = wdec_bf + (size_t)NV * NH;        // 2048*512  bf16
    unsigned short* wih_bf  = whh_bf + (size_t)G4 * NH;         // 2048*384  bf16
    unsigned short* hx      = wih_bf + (size_t)G4 * ECK;        // 64*128*512 bf16 (8 MB)
    unsigned int*   flags   = (unsigned int*)(hx + (size_t)NT * NB * NH);  // 64*8*32 u32

    hipMemsetAsync(hx, 0, NB * NH * sizeof(unsigned short), stream);       // hx[0] = h0 = 0
    hipMemsetAsync(flags, 0, (size_t)NT * 256 * sizeof(unsigned int), stream);
    hipMemsetAsync(sumexp, 0, BT * sizeof(float), stream);

    f32_to_bf16<<<(NV * NH / 4 + 255) / 256, 256, 0, stream>>>(W_dec, wdec_bf, NV * NH / 4);
    f32_to_bf16<<<(G4 * NH / 4 + 255) / 256, 256, 0, stream>>>(W_hh, whh_bf, G4 * NH / 4);
    f32_to_bf16<<<(G4 * ECK / 4 + 255) / 256, 256, 0, stream>>>(W_ih, wih_bf, G4 * ECK / 4);

    build_inp_bf<<<(BT * (ECK / 4) + 255) / 256, 256, 0, stream>>>(x, ctx, emb, inp_bf);

    gemm_xg_bf<<<dim3(G4 / 128, BT / 128), 256, 0, stream>>>(inp_bf, wih_bf, b_ih, b_hh, xg);

    lstm_persistent<<<256, 256, 0, stream>>>(whh_bf, xg, hx, hs_bf, flags);

    decoder_mfma<<<dim3(NV / 128, BT / 128), 256, 0, stream>>>(
        hs_bf, wdec_bf, b_dec, y, sumexp, picked);

    loss_kernel<<<1, 128, 0, stream>>>(picked, sumexp, out);
}

// Round 6
// 528.697 us; speedup vs baseline: 5.9360x; 1.1393x over previous
//
#include <hip/hip_runtime.h>
#include <cmath>

// Problem constants
#define NB   128      // batch
#define NT   64       // time
#define NV   16000    // vocab
#define NVP  16384    // vocab padded to 128 col-tiles (16 per XCD)
#define NE   128      // emb dim
#define NC   256      // context dim
#define NH   512      // hidden
#define G4   2048     // 4*NH
#define ECK  384      // NE+NC
#define BT   8192     // NB*NT

typedef __attribute__((ext_vector_type(8))) short bf16x8;
typedef __attribute__((ext_vector_type(4))) float f32x4;
typedef const void __attribute__((address_space(1)))* gptr_t;
typedef void __attribute__((address_space(3)))* sptr_t;

static __device__ __forceinline__ unsigned short f2bf(float f) {
    union { float f; unsigned u; } a; a.f = f;
    unsigned r = (a.u + 0x7fff + ((a.u >> 16) & 1)) >> 16;   // RNE
    return (unsigned short)r;
}

// ---------------------------------------------------------------------------
// K0: build inp_bf[t*128+b][384] = bf16(concat(emb_table[x[b][t]], context[b]))
// ---------------------------------------------------------------------------
__global__ void build_inp_bf(const int* __restrict__ x, const float* __restrict__ ctx,
                             const float* __restrict__ emb, unsigned short* __restrict__ inp) {
    int f = blockIdx.x * blockDim.x + threadIdx.x;   // float4 index
    const int total = BT * (ECK / 4);
    if (f >= total) return;
    int row = f / (ECK / 4);
    int c4  = f % (ECK / 4);
    int b = row & (NB - 1);
    int c = c4 * 4;
    float4 v;
    if (c < NE) {
        int t = row >> 7;
        int tok = x[b * NT + t];
        v = *(const float4*)(emb + tok * NE + c);
    } else {
        v = *(const float4*)(ctx + b * NC + (c - NE));
    }
    ushort4 o;
    o.x = f2bf(v.x); o.y = f2bf(v.y); o.z = f2bf(v.z); o.w = f2bf(v.w);
    ((ushort4*)inp)[f] = o;
}

// ---------------------------------------------------------------------------
// K0b: fp32 -> bf16 convert (W_dec, W_hh, W_ih)
// ---------------------------------------------------------------------------
__global__ void f32_to_bf16(const float* __restrict__ src, unsigned short* __restrict__ dst, int n4) {
    int i = blockIdx.x * blockDim.x + threadIdx.x;
    if (i >= n4) return;
    float4 v = ((const float4*)src)[i];
    ushort4 o;
    o.x = f2bf(v.x); o.y = f2bf(v.y); o.z = f2bf(v.z); o.w = f2bf(v.w);
    ((ushort4*)dst)[i] = o;
}

// ---------------------------------------------------------------------------
// K0c: padded decoder bias: bdp[v] = v<NV ? b_dec[v] : -100  (exp(-100)=0)
// ---------------------------------------------------------------------------
__global__ void pad_bdec(const float* __restrict__ b_dec, float* __restrict__ bdp) {
    int i = blockIdx.x * blockDim.x + threadIdx.x;
    if (i >= NVP) return;
    bdp[i] = (i < NV) ? b_dec[i] : -100.f;
}

// ---------------------------------------------------------------------------
// K1: xg = inp_bf @ W_ih^T + b_ih + b_hh  (bf16 MFMA, m97 structure, K=384)
// ---------------------------------------------------------------------------
__global__ __launch_bounds__(256, 2) void gemm_xg_bf(
    const unsigned short* __restrict__ A,   // inp_bf [BT][384]
    const unsigned short* __restrict__ Bw,  // wih_bf [2048][384]
    const float* __restrict__ b_ih, const float* __restrict__ b_hh,
    float* __restrict__ xg)                 // [BT][2048] f32
{
    __shared__ short As[128 * 64];
    __shared__ short Bs[128 * 64];
    const int tid  = threadIdx.x;
    const int lane = tid & 63;
    const int wv   = tid >> 6;
    const int wr   = wv >> 1, wc = wv & 1;
    const int rowBase = blockIdx.y * 128;
    const int colBase = blockIdx.x * 128;

    f32x4 acc[4][4];
#pragma unroll
    for (int m = 0; m < 4; m++)
#pragma unroll
        for (int n = 0; n < 4; n++) acc[m][n] = (f32x4){0.f, 0.f, 0.f, 0.f};

    for (int kb = 0; kb < ECK; kb += 64) {
#pragma unroll
        for (int i = 0; i < 4; ++i) {
            int f = tid + i * 256;
            int r = f >> 3, pc = f & 7;
            int lc = pc ^ (r & 7);
            const unsigned short* srcA = A  + (size_t)(rowBase + r) * ECK + kb + lc * 8;
            const unsigned short* srcB = Bw + (size_t)(colBase + r) * ECK + kb + lc * 8;
            __builtin_amdgcn_global_load_lds((gptr_t)srcA, (sptr_t)(As + f * 8), 16, 0, 0);
            __builtin_amdgcn_global_load_lds((gptr_t)srcB, (sptr_t)(Bs + f * 8), 16, 0, 0);
        }
        __syncthreads();
#pragma unroll
        for (int kk = 0; kk < 2; ++kk) {
            bf16x8 af[4], bfr[4];
#pragma unroll
            for (int m = 0; m < 4; ++m) {
                int r  = wr * 64 + m * 16 + (lane & 15);
                int pc = (kk * 4 + (lane >> 4)) ^ (r & 7);
                af[m] = *(const bf16x8*)(As + r * 64 + pc * 8);
            }
#pragma unroll
            for (int n = 0; n < 4; ++n) {
                int r  = wc * 64 + n * 16 + (lane & 15);
                int pc = (kk * 4 + (lane >> 4)) ^ (r & 7);
                bfr[n] = *(const bf16x8*)(Bs + r * 64 + pc * 8);
            }
#pragma unroll
            for (int m = 0; m < 4; ++m)
#pragma unroll
                for (int n = 0; n < 4; ++n)
                    acc[m][n] = __builtin_amdgcn_mfma_f32_16x16x32_bf16(af[m], bfr[n], acc[m][n], 0, 0, 0);
        }
        __syncthreads();
    }
    const int rBase = rowBase + wr * 64;
    const int cBase = colBase + wc * 64;
#pragma unroll
    for (int n = 0; n < 4; ++n) {
        int col = cBase + n * 16 + (lane & 15);
        float bias = b_ih[col] + b_hh[col];
#pragma unroll
        for (int m = 0; m < 4; ++m)
#pragma unroll
            for (int reg = 0; reg < 4; ++reg) {
                int row = rBase + m * 16 + (lane >> 4) * 4 + reg;
                xg[(size_t)row * G4 + col] = acc[m][n][reg] + bias;
            }
    }
}

// ---------------------------------------------------------------------------
// K2: persistent LSTM — all 64 timesteps in one kernel. (unchanged from r5)
// ---------------------------------------------------------------------------
__global__ __launch_bounds__(256, 1) void lstm_persistent(
    const unsigned short* __restrict__ whh_bf,      // [2048][512] bf16
    const float* __restrict__ xg,                   // [BT][2048] f32, row t*128+b
    unsigned short* __restrict__ hx,                // [NT][128][512] bf16 (hx[0] zeroed)
    unsigned short* __restrict__ hs_bf,             // [8192][512] bf16, row b*64+t
    unsigned int* __restrict__ flags)               // [NT][8][32] zeroed
{
    __shared__ short Ws[64 * 512];      // 64 KB W_hh slice (rows c=g*16+j)
    __shared__ short As[16 * 512];      // 16 KB staged h panel (chunk-swizzled)
    __shared__ float Cs[16][68];        // C scratch (padded: 2-way max)
    __shared__ float cst[256];          // persistent c state
    __shared__ unsigned short hpk[256]; // h patch pack buffer [b*16+j]
    const int tid  = threadIdx.x;
    const int lane = tid & 63;
    const int wv   = tid >> 6;
    const int bid  = blockIdx.x;
    const int bb = bid & 7;             // batch group -> same XCD (heuristic)
    const int hb = bid >> 3;            // h-slice
    const int hBase = hb * 16;
    const int bBase = bb * 16;

    unsigned long long* hx64 = (unsigned long long*)hx;

    // stage W slice once; LDS slot ch of row r holds logical chunk ch^(r&7)
#pragma unroll
    for (int i = 0; i < 16; ++i) {
        int f = tid + i * 256;
        int r = f >> 6, ch = f & 63;
        int g = r >> 4, j = r & 15;
        const unsigned short* src = whh_bf + (size_t)((g << 9) + hBase + j) * NH + ((ch ^ (r & 7)) << 3);
        __builtin_amdgcn_global_load_lds((gptr_t)src, (sptr_t)(Ws + f * 8), 16, 0, 0);
    }
    cst[tid] = 0.f;
    __syncthreads();

    const int gb = tid >> 4, gj = tid & 15;          // gate-stage mapping
    const int hAbs = hBase + gj;

#pragma unroll 1
    for (int t = 0; t < NT; ++t) {
        // --- prefetch xg for this step (barrier-independent; hides HBM latency)
        const float* xgr = xg + (size_t)(t * NB + bBase + gb) * G4 + hAbs;
        float x0 = xgr[0];
        float x1 = xgr[NH];
        float x2 = xgr[2 * NH];
        float x3 = xgr[3 * NH];

        // --- wait for step t's h panel (written at end of step t-1)
        if (t > 0) {
            const unsigned int* fl = flags + (size_t)(t - 1) * 256 + bb * 32;
            unsigned int v;
            do {
                v = __hip_atomic_load(&fl[lane & 31], __ATOMIC_RELAXED,
                                      __HIP_MEMORY_SCOPE_AGENT);
            } while (!__all(v != 0));
        }

        // --- stage h panel: NORMAL cached global_load_lds (w=16), swizzled source
        const unsigned short* hsrc = hx + (size_t)t * NB * NH;
#pragma unroll
        for (int i = 0; i < 4; ++i) {
            int f = tid + i * 256;
            int r = f >> 6, ch = f & 63;
            const unsigned short* src = hsrc + (size_t)(bBase + r) * NH + ((ch ^ (r & 7)) << 3);
            __builtin_amdgcn_global_load_lds((gptr_t)src, (sptr_t)(As + f * 8), 16, 0, 0);
        }
        __syncthreads();

        // --- C[16][64] = h(16x512) @ Ws(64x512)^T ; wave wv owns n-tile wv
        f32x4 acc = (f32x4){0.f, 0.f, 0.f, 0.f};
        const int ar = lane & 15;
        const int br = wv * 16 + (lane & 15);
#pragma unroll
        for (int kc = 0; kc < 16; ++kc) {
            int cA = (kc * 4 + (lane >> 4)) ^ (ar & 7);
            int cB = (kc * 4 + (lane >> 4)) ^ (br & 7);
            bf16x8 a = *(const bf16x8*)(As + ar * 512 + cA * 8);
            bf16x8 b = *(const bf16x8*)(Ws + br * 512 + cB * 8);
            acc = __builtin_amdgcn_mfma_f32_16x16x32_bf16(a, b, acc, 0, 0, 0);
        }
#pragma unroll
        for (int reg = 0; reg < 4; ++reg)
            Cs[(lane >> 4) * 4 + reg][wv * 16 + (lane & 15)] = acc[reg];
        __syncthreads();

        // --- gates (thread -> b=gb, j=gj) using prefetched xg
        {
            float gi = Cs[gb][gj]      + x0;
            float gf = Cs[gb][16 + gj] + x1;
            float gg = Cs[gb][32 + gj] + x2;
            float go = Cs[gb][48 + gj] + x3;
            float i_ = 1.f / (1.f + __expf(-gi));
            float f_ = 1.f / (1.f + __expf(-gf));
            float o_ = 1.f / (1.f + __expf(-go));
            float cp = cst[tid];
            float cn = f_ * cp + i_ * tanhf(gg);
            float hn = o_ * tanhf(cn);
            cst[tid] = cn;
            unsigned short h16 = f2bf(hn);
            hs_bf[((size_t)(bBase + gb) * NT + t) * NH + hAbs] = h16;  // normal store
            hpk[tid] = h16;
        }
        __syncthreads();

        // --- publish h patch -> hx[t+1] (agent atomics, write-through to IC),
        //     then per-producer flag (plain agent store, NO RMW)
        if (t < NT - 1) {
            if (wv == 0) {
                int b = lane >> 2, q = lane & 3;
                unsigned long long v = *(const unsigned long long*)&hpk[b * 16 + q * 4];
                __hip_atomic_store(
                    &hx64[(size_t)(t + 1) * NB * (NH / 4)
                          + (size_t)(bBase + b) * (NH / 4) + (hBase >> 2) + q],
                    v, __ATOMIC_RELAXED, __HIP_MEMORY_SCOPE_AGENT);
                asm volatile("s_waitcnt vmcnt(0)" ::: "memory");   // complete at IC
                if (lane == 0)
                    __hip_atomic_store(&flags[(size_t)t * 256 + bb * 32 + hb], 1u,
                                       __ATOMIC_RELAXED, __HIP_MEMORY_SCOPE_AGENT);
            }
            __syncthreads();   // hpk stable until wave0 consumed it
        }
    }
}

// ---------------------------------------------------------------------------
// K3: decoder GEMM (bf16 MFMA) + fused log-sum-exp.
// XCD-locality swizzle: 1-D grid 8192 blocks; hw maps bid->XCD round-robin
// (xcd = bid&7). idx = bid>>3: col = xcd*16 + (idx&15)  (16-col stripe per
// XCD -> B working set 2 MB, L2-resident), row = idx>>4 (16 consecutive
// blocks share one A panel). Vocab padded to 16384 (pad W rows=0, bias=-100).
// ---------------------------------------------------------------------------
__global__ __launch_bounds__(256, 2) void decoder_mfma(
    const unsigned short* __restrict__ A,   // hs_bf [BT][512]
    const unsigned short* __restrict__ Bw,  // W_dec_bf [NVP][512]
    const float* __restrict__ b_dec,        // padded [NVP]
    const int* __restrict__ y,
    float* __restrict__ sumexp,
    float* __restrict__ picked)
{
    __shared__ short As[128 * 64];
    __shared__ short Bs[128 * 64];
    const int tid  = threadIdx.x;
    const int lane = tid & 63;
    const int wv   = tid >> 6;
    const int wr   = wv >> 1, wc = wv & 1;
    const int bid  = blockIdx.x;
    const int xcd  = bid & 7;
    const int idx  = bid >> 3;
    const int rowBase = (idx >> 4) * 128;
    const int colBase = (xcd * 16 + (idx & 15)) * 128;

    f32x4 acc[4][4];
#pragma unroll
    for (int m = 0; m < 4; m++)
#pragma unroll
        for (int n = 0; n < 4; n++) acc[m][n] = (f32x4){0.f, 0.f, 0.f, 0.f};

    for (int kb = 0; kb < NH; kb += 64) {
#pragma unroll
        for (int i = 0; i < 4; ++i) {
            int f = tid + i * 256;
            int r = f >> 3, pc = f & 7;
            int lc = pc ^ (r & 7);
            const unsigned short* srcA = A  + (size_t)(rowBase + r) * NH + kb + lc * 8;
            const unsigned short* srcB = Bw + (size_t)(colBase + r) * NH + kb + lc * 8;
            __builtin_amdgcn_global_load_lds((gptr_t)srcA, (sptr_t)(As + f * 8), 16, 0, 0);
            __builtin_amdgcn_global_load_lds((gptr_t)srcB, (sptr_t)(Bs + f * 8), 16, 0, 0);
        }
        __syncthreads();
#pragma unroll
        for (int kk = 0; kk < 2; ++kk) {
            bf16x8 af[4], bfr[4];
#pragma unroll
            for (int m = 0; m < 4; ++m) {
                int r  = wr * 64 + m * 16 + (lane & 15);
                int pc = (kk * 4 + (lane >> 4)) ^ (r & 7);
                af[m] = *(const bf16x8*)(As + r * 64 + pc * 8);
            }
#pragma unroll
            for (int n = 0; n < 4; ++n) {
                int r  = wc * 64 + n * 16 + (lane & 15);
                int pc = (kk * 4 + (lane >> 4)) ^ (r & 7);
                bfr[n] = *(const bf16x8*)(Bs + r * 64 + pc * 8);
            }
#pragma unroll
            for (int m = 0; m < 4; ++m)
#pragma unroll
                for (int n = 0; n < 4; ++n)
                    acc[m][n] = __builtin_amdgcn_mfma_f32_16x16x32_bf16(af[m], bfr[n], acc[m][n], 0, 0, 0);
        }
        __syncthreads();
    }

    const int rBase = rowBase + wr * 64;
    const int cBase = colBase + wc * 64;
    int yv[4][4];
#pragma unroll
    for (int m = 0; m < 4; ++m)
#pragma unroll
        for (int reg = 0; reg < 4; ++reg)
            yv[m][reg] = y[rBase + m * 16 + (lane >> 4) * 4 + reg];

    float rs[4][4];
#pragma unroll
    for (int m = 0; m < 4; ++m)
#pragma unroll
        for (int reg = 0; reg < 4; ++reg) rs[m][reg] = 0.f;

#pragma unroll
    for (int n = 0; n < 4; ++n) {
        int v = cBase + n * 16 + (lane & 15);
        float bd = b_dec[v];
#pragma unroll
        for (int m = 0; m < 4; ++m)
#pragma unroll
            for (int reg = 0; reg < 4; ++reg) {
                float logit = acc[m][n][reg] + bd;
                if (v == yv[m][reg])
                    picked[rBase + m * 16 + (lane >> 4) * 4 + reg] = logit;
                rs[m][reg] += __expf(logit);
            }
    }
#pragma unroll
    for (int m = 0; m < 4; ++m)
#pragma unroll
        for (int reg = 0; reg < 4; ++reg) {
            float s = rs[m][reg];
            s += __shfl_xor(s, 1);
            s += __shfl_xor(s, 2);
            s += __shfl_xor(s, 4);
            s += __shfl_xor(s, 8);
            if ((lane & 15) == 0)
                atomicAdd(&sumexp[rBase + m * 16 + (lane >> 4) * 4 + reg], s);
        }
}

// ---------------------------------------------------------------------------
// K4: loss[b] = -sum_t (picked[b*T+t] - log(sumexp[b*T+t]))
// ---------------------------------------------------------------------------
__global__ void loss_kernel(const float* __restrict__ picked,
                            const float* __restrict__ sumexp,
                            float* __restrict__ out) {
    int b = threadIdx.x;
    if (b >= NB) return;
    float s = 0.f;
    for (int t = 0; t < NT; t++) {
        int r = b * NT + t;
        s += picked[r] - logf(sumexp[r]);
    }
    out[b] = -s;
}

// ---------------------------------------------------------------------------
extern "C" void kernel_launch(void* const* d_in, const int* in_sizes, int n_in,
                              void* d_out, int out_size, void* d_ws, size_t ws_size,
                              hipStream_t stream) {
    const int*   x     = (const int*)d_in[0];
    const int*   y     = (const int*)d_in[1];
    const float* ctx   = (const float*)d_in[2];
    const float* emb   = (const float*)d_in[3];
    const float* W_ih  = (const float*)d_in[4];
    const float* W_hh  = (const float*)d_in[5];
    const float* b_ih  = (const float*)d_in[6];
    const float* b_hh  = (const float*)d_in[7];
    const float* W_dec = (const float*)d_in[8];
    const float* b_dec = (const float*)d_in[9];
    float* out = (float*)d_out;

    // workspace carve
    float*          ws      = (float*)d_ws;
    float*          xg      = ws;                               // 8192*2048 f32 (64 MB)
    float*          sumexp  = xg + (size_t)BT * G4;             // 8192 f32
    float*          picked  = sumexp + BT;                      // 8192 f32
    float*          bdp     = picked + BT;                      // 16384 f32 padded bias
    unsigned short* inp_bf  = (unsigned short*)(bdp + NVP);     // 8192*384  bf16
    unsigned short* hs_bf   = inp_bf + (size_t)BT * ECK;        // 8192*512  bf16
    unsigned short* wdec_bf = hs_bf + (size_t)BT * NH;          // 16384*512 bf16 (padded)
    unsigned short* whh_bf  = wdec_bf + (size_t)NVP * NH;       // 2048*512  bf16
    unsigned short* wih_bf  = whh_bf + (size_t)G4 * NH;         // 2048*384  bf16
    unsigned short* hx      = wih_bf + (size_t)G4 * ECK;        // 64*128*512 bf16 (8 MB)
    unsigned int*   flags   = (unsigned int*)(hx + (size_t)NT * NB * NH);  // 64*8*32 u32

    hipMemsetAsync(hx, 0, NB * NH * sizeof(unsigned short), stream);       // hx[0] = h0 = 0
    hipMemsetAsync(flags, 0, (size_t)NT * 256 * sizeof(unsigned int), stream);
    hipMemsetAsync(sumexp, 0, BT * sizeof(float), stream);
    // zero W_dec pad rows (16000..16383)
    hipMemsetAsync(wdec_bf + (size_t)NV * NH, 0, (size_t)(NVP - NV) * NH * sizeof(unsigned short), stream);

    pad_bdec<<<(NVP + 255) / 256, 256, 0, stream>>>(b_dec, bdp);

    f32_to_bf16<<<(NV * NH / 4 + 255) / 256, 256, 0, stream>>>(W_dec, wdec_bf, NV * NH / 4);
    f32_to_bf16<<<(G4 * NH / 4 + 255) / 256, 256, 0, stream>>>(W_hh, whh_bf, G4 * NH / 4);
    f32_to_bf16<<<(G4 * ECK / 4 + 255) / 256, 256, 0, stream>>>(W_ih, wih_bf, G4 * ECK / 4);

    build_inp_bf<<<(BT * (ECK / 4) + 255) / 256, 256, 0, stream>>>(x, ctx, emb, inp_bf);

    gemm_xg_bf<<<dim3(G4 / 128, BT / 128), 256, 0, stream>>>(inp_bf, wih_bf, b_ih, b_hh, xg);

    lstm_persistent<<<256, 256, 0, stream>>>(whh_bf, xg, hx, hs_bf, flags);

    decoder_mfma<<<(NVP / 128) * (BT / 128), 256, 0, stream>>>(
        hs_bf, wdec_bf, bdp, y, sumexp, picked);

    loss_kernel<<<1, 128, 0, stream>>>(picked, sumexp, out);
}